// Round 17
// baseline (346.397 us; speedup 1.0000x reference)
//
#include <hip/hip_runtime.h>

// Problem constants
#define BB     2
#define CC     256
#define HH     48
#define WW     48
#define NTOK   2304          // H*W
#define NHEADS 8
#define HDIM   32
#define NBH    16            // BB*NHEADS
#define SCALE_QK 0.17677669529663687f  // 1/sqrt(32)
#define KSEL1  1152          // N1 // 2
#define KSEL2  768           // N1 // 3
#define NBIN   512
#define GCAP   192
#define LOSCALE 2048.0f      // 2^11: keeps f16 lo-parts in normal range

typedef _Float16 f16x8 __attribute__((ext_vector_type(8)));
typedef float f32x4 __attribute__((ext_vector_type(4)));

// Fixed-range value binning: scores ~N(0,0.1); [-1,1)/512 bins -> densest
// bin ~36 elems; clamp bins catch outliers; GCAP fallback keeps exactness.
// NOTE (r7): LDS histogram atomics must be integer (f32 atomicAdd = CAS loop).
// NOTE (r12): no per-element exp; D = bin-center approx + exact boundary.
// NOTE (r15->r16): intra-wave cross-lane LDS handoff needs explicit
// lgkmcnt(0)+sched_barrier fences (no-return atomics carry no dependency).
// NOTE (r17): CH=4 so the sc slice (42.5 MB) stays L3-resident for
// select/pv; MSPLIT=8 keeps pv at 1152 blocks/dispatch.
__device__ __forceinline__ int binof(float v) {
  int b = (int)((v + 1.0f) * 256.0f);
  return min(max(b, 0), NBIN - 1);
}

// Intra-wave LDS fence: all lanes have ISSUED their DS ops (lockstep);
// drain them and forbid compiler motion across this point.
__device__ __forceinline__ void wave_lds_fence() {
  __builtin_amdgcn_sched_barrier(0);
  asm volatile("s_waitcnt lgkmcnt(0)" ::: "memory");
  __builtin_amdgcn_sched_barrier(0);
}

// ---------------------------------------------------------------------------
// Kernel A: multi-scale avg pool (3,5,7 box filters, count_include_pad) via
// per-plane integral image. One block per (b,c) plane.
__global__ __launch_bounds__(256) void pool_kernel(const float* __restrict__ y,
                                                   float* __restrict__ yp) {
  __shared__ float sp[HH * WW];
  __shared__ float I[49 * 49];
  const int bc = blockIdx.x;
  const float* src = y + (size_t)bc * (HH * WW);
  for (int i = threadIdx.x; i < HH * WW; i += 256) sp[i] = src[i];
  __syncthreads();
  if (threadIdx.x < 48) {            // row prefix sums
    int r = threadIdx.x;
    float acc = 0.f;
    I[(r + 1) * 49 + 0] = 0.f;
    for (int j = 0; j < 48; ++j) { acc += sp[r * 48 + j]; I[(r + 1) * 49 + j + 1] = acc; }
  } else if (threadIdx.x < 97) {     // zero top row
    int j = threadIdx.x - 48;
    I[j] = 0.f;
  }
  __syncthreads();
  if (threadIdx.x < 48) {            // column prefix sums
    int j = threadIdx.x + 1;
    float acc = 0.f;
    for (int i = 1; i <= 48; ++i) { acc += I[i * 49 + j]; I[i * 49 + j] = acc; }
  }
  __syncthreads();
  for (int n = threadIdx.x; n < HH * WW; n += 256) {
    int i = n / 48, j = n % 48;
    float r = 0.f;
#pragma unroll
    for (int kk = 0; kk < 3; ++kk) {
      int p = 1 + kk;                 // kernel 3,5,7 -> pad 1,2,3
      int i0 = i - p; if (i0 < 0) i0 = 0;
      int j0 = j - p; if (j0 < 0) j0 = 0;
      int i1 = i + p + 1; if (i1 > 48) i1 = 48;
      int j1 = j + p + 1; if (j1 > 48) j1 = 48;
      float s = I[i1 * 49 + j1] - I[i0 * 49 + j1] - I[i1 * 49 + j0] + I[i0 * 49 + j0];
      int k = 2 * p + 1;
      r += s / (float)(k * k);
    }
    yp[(size_t)bc * (HH * WW) + n] = r;
  }
}

// ---------------------------------------------------------------------------
// Kernel B: coalesced LayerNorm over C with LDS tile; writes f16 hi/lo.
__global__ __launch_bounds__(256) void ln_kernel(const float* __restrict__ yp,
                                                 const float* __restrict__ gamma,
                                                 const float* __restrict__ beta,
                                                 _Float16* __restrict__ yth,
                                                 _Float16* __restrict__ ytl) {
  __shared__ float tile[CC][33];
  __shared__ float part[8][32];
  __shared__ float part2[8][32];
  const int b = blockIdx.y;
  const int n0 = blockIdx.x * 32;
  const int tid = threadIdx.x;
#pragma unroll
  for (int it = 0; it < 32; ++it) {
    int idx = it * 256 + tid;
    int c = idx >> 5, nl = idx & 31;
    tile[c][nl] = yp[((size_t)(b * CC + c)) * NTOK + n0 + nl];
  }
  __syncthreads();
  const int nl = tid & 31, cs = tid >> 5;   // 8 c-slices of 32
  float s = 0.f, s2 = 0.f;
#pragma unroll
  for (int i = 0; i < 32; ++i) {
    float v = tile[cs * 32 + i][nl];
    s += v; s2 += v * v;
  }
  part[cs][nl] = s; part2[cs][nl] = s2;
  __syncthreads();
  float S = 0.f, S2 = 0.f;
#pragma unroll
  for (int i = 0; i < 8; ++i) { S += part[i][nl]; S2 += part2[i][nl]; }
  const float mean = S * (1.f / CC);
  const float var = S2 * (1.f / CC) - mean * mean;
  const float rstd = rsqrtf(var + 1e-5f);
  const size_t dstb = ((size_t)(b * NTOK + n0 + nl)) * CC + cs * 32;
#pragma unroll
  for (int g8 = 0; g8 < 4; ++g8) {
    f16x8 vh, vl;
#pragma unroll
    for (int e = 0; e < 8; ++e) {
      int c = cs * 32 + g8 * 8 + e;
      float o = (tile[c][nl] - mean) * rstd * gamma[c] + beta[c];
      _Float16 hi = (_Float16)o;
      vh[e] = hi;
      vl[e] = (_Float16)((o - (float)hi) * LOSCALE);
    }
    *(f16x8*)(yth + dstb + g8 * 8) = vh;
    *(f16x8*)(ytl + dstb + g8 * 8) = vl;
  }
}

// ---------------------------------------------------------------------------
// Kernel X: x [b][c][n] -> xh/xl [b][n][c] f16 hi/lo (LDS tile transpose).
__global__ __launch_bounds__(256) void xcast_kernel(const float* __restrict__ x,
                                                    _Float16* __restrict__ xh,
                                                    _Float16* __restrict__ xl) {
  __shared__ float tile[64][65];
  const int b = blockIdx.z;
  const int nb = blockIdx.x;   // 36 tiles of 64 n
  const int cb = blockIdx.y;   // 4 tiles of 64 c
  const int tid = threadIdx.x;
#pragma unroll
  for (int it = 0; it < 16; ++it) {
    int idx = it * 256 + tid;
    int cl = idx >> 6, nl = idx & 63;
    tile[cl][nl] = x[((size_t)(b * CC + cb * 64 + cl)) * NTOK + nb * 64 + nl];
  }
  __syncthreads();
#pragma unroll
  for (int it = 0; it < 16; ++it) {
    int idx = it * 256 + tid;
    int nl = idx >> 6, cl = idx & 63;
    float v = tile[cl][nl];
    size_t dst = ((size_t)(b * NTOK + nb * 64 + nl)) * CC + cb * 64 + cl;
    _Float16 hi = (_Float16)v;
    xh[dst] = hi;
    xl[dst] = (_Float16)((v - (float)hi) * LOSCALE);
  }
}

// ---------------------------------------------------------------------------
// Kernel W: ALL THREE weight transpose-casts in one launch.
__global__ __launch_bounds__(256) void wtcast3_kernel(
    const float* __restrict__ Wq, const float* __restrict__ Wkv,
    const float* __restrict__ Wproj,
    _Float16* __restrict__ wqh, _Float16* __restrict__ wql,
    _Float16* __restrict__ wkvh, _Float16* __restrict__ wkvl,
    _Float16* __restrict__ wph, _Float16* __restrict__ wpl) {
  const int blk = blockIdx.x;
  const int k = threadIdx.x;
  const float* W; _Float16 *wh, *wl; int ncol, col; float scale;
  if (blk < CC)            { W = Wq;    wh = wqh;  wl = wql;  ncol = CC;     col = blk;          scale = SCALE_QK; }
  else if (blk < 3 * CC)   { W = Wkv;   wh = wkvh; wl = wkvl; ncol = 2 * CC; col = blk - CC;     scale = 1.0f; }
  else                     { W = Wproj; wh = wph;  wl = wpl;  ncol = CC;     col = blk - 3 * CC; scale = 1.0f; }
  float v = W[(size_t)k * ncol + col] * scale;
  _Float16 hi = (_Float16)v;
  wh[(size_t)col * CC + k] = hi;
  wl[(size_t)col * CC + k] = (_Float16)((v - (float)hi) * LOSCALE);
}

// ---------------------------------------------------------------------------
// Kernel G: hi/lo split-precision MFMA GEMM, zero LDS (except MODE 2
// transpose epilogue). C = A[M=4608][K=256] @ B[K=256][ncol].
// MODE 0 (q):   A from Ah/Al; out -> Oh/Ol score-layout split
// MODE 1 (kv):  A from Ah/Al; col<256 -> k table; col>=256 -> vtb direct
// MODE 2 (proj): A from f32 Af (hi/lo split in-register);
//                Of[b][col][n] = out + bias[col] (LDS-transposed store)
template <int MODE>
__global__ __launch_bounds__(256) void gemm_hilo_kernel(
    const _Float16* __restrict__ Ah, const _Float16* __restrict__ Al,
    const float* __restrict__ Af,
    const _Float16* __restrict__ Bh, const _Float16* __restrict__ Bl,
    const float* __restrict__ bias,
    _Float16* __restrict__ Oh, _Float16* __restrict__ Ol,
    _Float16* __restrict__ Ov, float* __restrict__ Of) {
  const int w = threadIdx.x >> 6;
  const int lane = threadIdx.x & 63;
  const int wm = w >> 1, wc = w & 1;
  const int r16 = lane & 15, kg = lane >> 4;
  const int m0 = blockIdx.x * 64 + wm * 32;
  const int c0 = blockIdx.y * 64 + wc * 32;
  const f32x4 fz = {0.f, 0.f, 0.f, 0.f};
  f32x4 acc00 = fz, acc01 = fz, acc10 = fz, acc11 = fz;
  f32x4 ac200 = fz, ac201 = fz, ac210 = fz, ac211 = fz;
  for (int ks = 0; ks < CC; ks += 32) {
    f16x8 ah_[2], al_[2], bh_[2], bl_[2];
#pragma unroll
    for (int i = 0; i < 2; ++i) {
      size_t offa = (size_t)(m0 + i * 16 + r16) * CC + ks + kg * 8;
      if constexpr (MODE == 2) {
        f32x4 a0 = *(const f32x4*)(Af + offa);
        f32x4 a1 = *(const f32x4*)(Af + offa + 4);
#pragma unroll
        for (int e = 0; e < 4; ++e) {
          _Float16 h0 = (_Float16)a0[e];
          ah_[i][e] = h0;
          al_[i][e] = (_Float16)((a0[e] - (float)h0) * LOSCALE);
          _Float16 h1 = (_Float16)a1[e];
          ah_[i][e + 4] = h1;
          al_[i][e + 4] = (_Float16)((a1[e] - (float)h1) * LOSCALE);
        }
      } else {
        ah_[i] = *(const f16x8*)(Ah + offa);
        al_[i] = *(const f16x8*)(Al + offa);
      }
      size_t offb = (size_t)(c0 + i * 16 + r16) * CC + ks + kg * 8;
      bh_[i] = *(const f16x8*)(Bh + offb);
      bl_[i] = *(const f16x8*)(Bl + offb);
    }
    acc00 = __builtin_amdgcn_mfma_f32_16x16x32_f16(ah_[0], bh_[0], acc00, 0, 0, 0);
    ac200 = __builtin_amdgcn_mfma_f32_16x16x32_f16(ah_[0], bl_[0], ac200, 0, 0, 0);
    ac200 = __builtin_amdgcn_mfma_f32_16x16x32_f16(al_[0], bh_[0], ac200, 0, 0, 0);
    acc01 = __builtin_amdgcn_mfma_f32_16x16x32_f16(ah_[0], bh_[1], acc01, 0, 0, 0);
    ac201 = __builtin_amdgcn_mfma_f32_16x16x32_f16(ah_[0], bl_[1], ac201, 0, 0, 0);
    ac201 = __builtin_amdgcn_mfma_f32_16x16x32_f16(al_[0], bh_[1], ac201, 0, 0, 0);
    acc10 = __builtin_amdgcn_mfma_f32_16x16x32_f16(ah_[1], bh_[0], acc10, 0, 0, 0);
    ac210 = __builtin_amdgcn_mfma_f32_16x16x32_f16(ah_[1], bl_[0], ac210, 0, 0, 0);
    ac210 = __builtin_amdgcn_mfma_f32_16x16x32_f16(al_[1], bh_[0], ac210, 0, 0, 0);
    acc11 = __builtin_amdgcn_mfma_f32_16x16x32_f16(ah_[1], bh_[1], acc11, 0, 0, 0);
    ac211 = __builtin_amdgcn_mfma_f32_16x16x32_f16(ah_[1], bl_[1], ac211, 0, 0, 0);
    ac211 = __builtin_amdgcn_mfma_f32_16x16x32_f16(al_[1], bh_[1], ac211, 0, 0, 0);
  }
  f32x4 accs[2][2] = {{acc00, acc01}, {acc10, acc11}};
  f32x4 ac2s[2][2] = {{ac200, ac201}, {ac210, ac211}};
  if constexpr (MODE == 2) {
    __shared__ float ts[4][32][33];
#pragma unroll
    for (int i = 0; i < 2; ++i)
#pragma unroll
      for (int j = 0; j < 2; ++j)
#pragma unroll
        for (int r = 0; r < 4; ++r)
          ts[w][i * 16 + kg * 4 + r][j * 16 + r16] =
              accs[i][j][r] + ac2s[i][j][r] * (1.f / LOSCALE);
    __syncthreads();
    const int b = m0 / NTOK;
    const int n_base = m0 % NTOK;
#pragma unroll
    for (int t = 0; t < 16; ++t) {
      int idx = t * 64 + lane;
      int ml = idx & 31, cl = idx >> 5;
      float v = ts[w][ml][cl] + bias[c0 + cl];
      Of[((size_t)(b * CC + c0 + cl)) * NTOK + n_base + ml] = v;
    }
  } else {
#pragma unroll
    for (int i = 0; i < 2; ++i) {
#pragma unroll
      for (int j = 0; j < 2; ++j) {
#pragma unroll
        for (int r = 0; r < 4; ++r) {
          float val = accs[i][j][r] + ac2s[i][j][r] * (1.f / LOSCALE);
          int m = m0 + i * 16 + kg * 4 + r;
          int c = c0 + j * 16 + r16;
          int b = m / NTOK, n = m % NTOK;
          if (MODE == 0 || c < CC) {
            int h = (c & (CC - 1)) >> 5, d = c & 31;
            size_t dst = ((size_t)((b * 8 + h) * NTOK) + n) * HDIM + d;
            _Float16 hi = (_Float16)val;
            Oh[dst] = hi;
            Ol[dst] = (_Float16)((val - (float)hi) * LOSCALE);
          } else {
            int cc2 = c - CC;
            int h2 = cc2 >> 5, d2 = cc2 & 31;
            Ov[((size_t)((b * NHEADS + h2) * HDIM + d2)) * NTOK + n] = (_Float16)val;
          }
        }
      }
    }
  }
}

// ---------------------------------------------------------------------------
// Kernel D: scores via MFMA with f16 hi/lo split precision, stored as f16.
// Zero LDS. Wave = 32n x 32m (2x2 tiles of 16x16x32); block = 4 waves =
// 64n x 64m, m-loop x4 -> 64n x 256m.
#define SMSTEP 4
__global__ __launch_bounds__(256) void score_mfma_kernel(const _Float16* __restrict__ qh,
                                                         const _Float16* __restrict__ ql,
                                                         const _Float16* __restrict__ kh,
                                                         const _Float16* __restrict__ kl,
                                                         _Float16* __restrict__ sc, int bh0) {
  const int w = threadIdx.x >> 6;
  const int lane = threadIdx.x & 63;
  const int wn = w >> 1, wm = w & 1;
  const int r16 = lane & 15, kg = lane >> 4;
  const int z = blockIdx.z;
  const int gbh = bh0 + z;
  const size_t tb = (size_t)gbh * NTOK * HDIM;
  const int n0 = blockIdx.x * 64 + wn * 32;
  const f32x4 fz = {0.f, 0.f, 0.f, 0.f};
  f16x8 ah[2], al[2];
#pragma unroll
  for (int i = 0; i < 2; ++i) {
    size_t off = tb + (size_t)(n0 + i * 16 + r16) * HDIM + kg * 8;
    ah[i] = *(const f16x8*)(qh + off);
    al[i] = *(const f16x8*)(ql + off);
  }
  for (int s = 0; s < SMSTEP; ++s) {
    const int ms = blockIdx.y * (SMSTEP * 64) + s * 64 + wm * 32;
    f16x8 bhf[2], blf[2];
#pragma unroll
    for (int j = 0; j < 2; ++j) {
      size_t off = tb + (size_t)(ms + j * 16 + r16) * HDIM + kg * 8;
      bhf[j] = *(const f16x8*)(kh + off);
      blf[j] = *(const f16x8*)(kl + off);
    }
#pragma unroll
    for (int i = 0; i < 2; ++i)
#pragma unroll
      for (int j = 0; j < 2; ++j) {
        f32x4 acc = __builtin_amdgcn_mfma_f32_16x16x32_f16(ah[i], bhf[j], fz, 0, 0, 0);
        f32x4 ac2 = __builtin_amdgcn_mfma_f32_16x16x32_f16(ah[i], blf[j], fz, 0, 0, 0);
        ac2 = __builtin_amdgcn_mfma_f32_16x16x32_f16(al[i], bhf[j], ac2, 0, 0, 0);
        // C layout: row=(lane>>4)*4+r (q row), col=lane&15 (m col)
        size_t rowbase = ((size_t)z * NTOK + n0 + i * 16 + kg * 4) * NTOK + ms + j * 16 + r16;
#pragma unroll
        for (int r = 0; r < 4; ++r)
          sc[rowbase + (size_t)r * NTOK] = (_Float16)(acc[r] + ac2[r] * (1.0f / LOSCALE));
      }
  }
}

// ---------------------------------------------------------------------------
// Suffix-scan bucket finder over NB=NPL*64 bins: finds bucket where the
// descending cumulative count crosses krem. Writes {bucket, new_krem}.
// Wave-local; caller must fence before reading sres2.
template <int NPL>
__device__ __forceinline__ void radix_find(const unsigned* __restrict__ h,
                                           unsigned krem, unsigned* sres2) {
  const int lane = threadIdx.x & 63;
  unsigned c[NPL];
#pragma unroll
  for (int i = 0; i < NPL; ++i) c[i] = h[lane * NPL + i];
  unsigned suf[NPL];
  unsigned run = 0;
#pragma unroll
  for (int i = NPL - 1; i >= 0; --i) { run += c[i]; suf[i] = run; }
  unsigned acc = run;
#pragma unroll
  for (int off = 1; off < 64; off <<= 1) {
    unsigned t = __shfl_down(acc, off);
    if (lane + off < 64) acc += t;
  }
  unsigned tail = __shfl_down(acc, 1);
  if (lane == 63) tail = 0;
#pragma unroll
  for (int i = 0; i < NPL; ++i) {
    unsigned s = tail + suf[i];
    unsigned nx = (i + 1 < NPL) ? (tail + suf[i + 1]) : tail;
    if (s >= krem && nx < krem) {
      sres2[0] = (unsigned)(lane * NPL + i);
      sres2[1] = krem - nx;
    }
  }
}

// ---------------------------------------------------------------------------
// Kernel E (r16): WAVE-PER-ROW select with explicit intra-wave LDS fences.
// Block = 4 waves = 4 rows; zero __syncthreads.
__global__ __launch_bounds__(256) void select_kernel(const _Float16* __restrict__ sc,
                                                     float* __restrict__ stats,
                                                     const float* __restrict__ w1p,
                                                     const float* __restrict__ w2p) {
  __shared__ unsigned cnt[4][NBIN];
  __shared__ float buf[4][2][GCAP];
  __shared__ unsigned bcnt[4][2];
  __shared__ unsigned sres[4][4];
  __shared__ float tthr[4][2];
  const int tid = threadIdx.x;
  const int wv = tid >> 6, lane = tid & 63;
  const int row = blockIdx.x * 4 + wv;
  const size_t base = (size_t)row * NTOK;
  unsigned* mycnt = cnt[wv];
#pragma unroll
  for (int i = 0; i < NBIN / 64; ++i) mycnt[lane * (NBIN / 64) + i] = 0u;
  if (lane < 2) bcnt[wv][lane] = 0u;
  wave_lds_fence();                       // zeroing visible before atomics
  // load row into registers: 288 f16x8 groups; 4/lane + 1 extra for lane<32
  f16x8 r[4];
#pragma unroll
  for (int j = 0; j < 4; ++j) r[j] = *((const f16x8*)(sc + base) + j * 64 + lane);
  const bool two = (lane < 32);
  f16x8 r4 = two ? *((const f16x8*)(sc + base) + 256 + lane) : f16x8{};
  // count histogram (u32 LDS atomics, wave-private region)
#pragma unroll
  for (int j = 0; j < 4; ++j)
#pragma unroll
    for (int e = 0; e < 8; ++e) atomicAdd(&mycnt[binof((float)r[j][e])], 1u);
  if (two) {
#pragma unroll
    for (int e = 0; e < 8; ++e) atomicAdd(&mycnt[binof((float)r4[e])], 1u);
  }
  wave_lds_fence();                       // histogram visible before reads
  // both selections' boundary buckets
  radix_find<NBIN / 64>(mycnt, KSEL1, &sres[wv][0]);
  radix_find<NBIN / 64>(mycnt, KSEL2, &sres[wv][2]);
  wave_lds_fence();                       // sres visible to all lanes
  const int b1 = (int)sres[wv][0], b2 = (int)sres[wv][2];
  const unsigned k1 = sres[wv][1], k2 = sres[wv][3];
  const unsigned c1 = mycnt[b1], c2 = mycnt[b2];
  const bool g1ok = (c1 <= GCAP), g2ok = (c2 <= GCAP);
  const float lo1 = (b1 == 0) ? -3.4e38f : ((float)b1 * (1.f / 256.f) - 1.f);
  const float hi1 = (b1 == NBIN - 1) ? 3.4e38f : ((float)(b1 + 1) * (1.f / 256.f) - 1.f);
  const float lo2 = (b2 == 0) ? -3.4e38f : ((float)b2 * (1.f / 256.f) - 1.f);
  const float hi2 = (b2 == NBIN - 1) ? 3.4e38f : ((float)(b2 + 1) * (1.f / 256.f) - 1.f);
  // gather boundary-bucket elements from registers
#pragma unroll
  for (int j = 0; j < 4; ++j)
#pragma unroll
    for (int e = 0; e < 8; ++e) {
      float v = (float)r[j][e];
      if (g1ok && v >= lo1 && v < hi1) buf[wv][0][atomicAdd(&bcnt[wv][0], 1u)] = v;
      if (g2ok && v >= lo2 && v < hi2) buf[wv][1][atomicAdd(&bcnt[wv][1], 1u)] = v;
    }
  if (two) {
#pragma unroll
    for (int e = 0; e < 8; ++e) {
      float v = (float)r4[e];
      if (g1ok && v >= lo1 && v < hi1) buf[wv][0][atomicAdd(&bcnt[wv][0], 1u)] = v;
      if (g2ok && v >= lo2 && v < hi2) buf[wv][1][atomicAdd(&bcnt[wv][1], 1u)] = v;
    }
  }
  wave_lds_fence();                       // gathered buf visible
  // exact k-th within boundary bucket (both sels, serial per wave)
#pragma unroll
  for (int sel = 0; sel < 2; ++sel) {
    const unsigned kk = sel ? k2 : k1;
    const int bb = sel ? b2 : b1;
    const unsigned cc = sel ? c2 : c1;
    if (cc <= GCAP) {
      for (unsigned i = lane; i < cc; i += 64) {
        float xv = buf[wv][sel][i];
        unsigned g = 0, m = 0;
        for (unsigned j2 = 0; j2 < cc; ++j2) {
          float yv = buf[wv][sel][j2];   // same-address broadcast
          g += (yv > xv) ? 1u : 0u;
          m += (yv == xv) ? 1u : 0u;
        }
        if (g < kk && kk <= g + m) tthr[wv][sel] = xv;
      }
    } else {
      // exact fallback: re-read row from global (degenerate data only)
      for (int i = lane; i < NTOK; i += 64) {
        float xv = (float)sc[base + i];
        if (binof(xv) != bb) continue;
        unsigned g = 0, m = 0;
        for (int j2 = 0; j2 < NTOK; ++j2) {
          float yv = (float)sc[base + j2];
          if (binof(yv) != bb) continue;
          g += (yv > xv) ? 1u : 0u;
          m += (yv == xv) ? 1u : 0u;
        }
        if (g < kk && kk <= g + m) tthr[wv][sel] = xv;
      }
    }
  }
  wave_lds_fence();                       // tthr visible
  // D = suffix of cnt[b]*exp(center_b) + exact boundary partial (both sels)
  float D[2];
#pragma unroll
  for (int sel = 0; sel < 2; ++sel) {
    const int bb = sel ? b2 : b1;
    const unsigned cc = sel ? c2 : c1;
    const float t = tthr[wv][sel];
    float ps = 0.f;
    if (cc <= GCAP) {
      for (unsigned i = lane; i < cc; i += 64) {
        float xv = buf[wv][sel][i];
        if (xv >= t) ps += __expf(xv);
      }
    } else {
      for (int i = lane; i < NTOK; i += 64) {
        float xv = (float)sc[base + i];
        if (binof(xv) == bb && xv >= t) ps += __expf(xv);
      }
    }
    for (int b = bb + 1 + lane; b < NBIN; b += 64)
      ps += (float)mycnt[b] * __expf((float)b * (1.f / 256.f) + (0.5f / 256.f) - 1.f);
#pragma unroll
    for (int off = 32; off; off >>= 1) ps += __shfl_down(ps, off);
    D[sel] = ps;
  }
  if (lane == 0) {
    float* st = stats + (size_t)row * 8;
    st[0] = 0.f;
    st[1] = tthr[wv][0];
    st[2] = tthr[wv][1];
    st[3] = w1p[0] / D[0];
    st[4] = w2p[0] / D[1];
  }
}

// ---------------------------------------------------------------------------
// Kernel F: PV via MFMA, zero LDS. Wave w of each block owns a 16(n) x 32(d)
// output tile. m-split over blockIdx.y, atomicAdd combine into zeroed oat.
#define MSPLIT 8
__global__ __launch_bounds__(256) void pv_mfma_kernel(const _Float16* __restrict__ sc,
                                                      const _Float16* __restrict__ vtb,
                                                      const float* __restrict__ stats,
                                                      float* __restrict__ oat, int bh0) {
  const int w = threadIdx.x >> 6;
  const int l = threadIdx.x & 63;
  const int z = blockIdx.z;
  const int gbh = bh0 + z;
  const int b = gbh >> 3, h = gbh & 7;
  const int n0 = blockIdx.x * 64 + w * 16;
  const int row = l & 15;            // A row / C col (d within half)
  const int kg = l >> 4;             // k-group
  const int n = n0 + row;
  const float* st = stats + ((size_t)z * NTOK + n) * 8;
  const float mx = st[0], t1 = st[1], t2 = st[2], w1d = st[3], w2d = st[4];
  const _Float16* srow = sc + ((size_t)z * NTOK + n) * NTOK;
  const _Float16* v0 = vtb + ((size_t)gbh * HDIM + row) * NTOK;
  const _Float16* v1 = v0 + 16 * NTOK;
  f32x4 acc0 = {0.f, 0.f, 0.f, 0.f};
  f32x4 acc1 = {0.f, 0.f, 0.f, 0.f};
  const int msteps = (NTOK / 32) / MSPLIT;   // 9
  int m0 = blockIdx.y * msteps * 32 + kg * 8;
#pragma unroll 3
  for (int s = 0; s < msteps; ++s, m0 += 32) {
    f16x8 sv8 = *(const f16x8*)(srow + m0);
    f16x8 afr;
#pragma unroll
    for (int i = 0; i < 8; ++i) {
      float sv = (float)sv8[i];
      float e = __expf(sv - mx);
      float wgt = (sv >= t1 ? w1d : 0.f) + (sv >= t2 ? w2d : 0.f);
      afr[i] = (_Float16)(e * wgt);
    }
    f16x8 bfr0 = *(const f16x8*)(v0 + m0);
    f16x8 bfr1 = *(const f16x8*)(v1 + m0);
    acc0 = __builtin_amdgcn_mfma_f32_16x16x32_f16(afr, bfr0, acc0, 0, 0, 0);
    acc1 = __builtin_amdgcn_mfma_f32_16x16x32_f16(afr, bfr1, acc1, 0, 0, 0);
  }
  // C/D layout: col = lane&15 (=row var), row = (lane>>4)*4 + reg
#pragma unroll
  for (int r = 0; r < 4; ++r) {
    int nn = n0 + kg * 4 + r;
    float* dst = &oat[((size_t)(b * NTOK + nn)) * CC + h * HDIM];
    atomicAdd(&dst[row], acc0[r]);
    atomicAdd(&dst[16 + row], acc1[r]);
  }
}

// ---------------------------------------------------------------------------
extern "C" void kernel_launch(void* const* d_in, const int* in_sizes, int n_in,
                              void* d_out, int out_size, void* d_ws, size_t ws_size,
                              hipStream_t stream) {
  const float* x     = (const float*)d_in[0];
  const float* y     = (const float*)d_in[1];
  const float* Wq    = (const float*)d_in[2];
  const float* Wkv   = (const float*)d_in[3];
  const float* Wproj = (const float*)d_in[4];
  const float* bproj = (const float*)d_in[5];
  const float* gamma = (const float*)d_in[6];
  const float* beta  = (const float*)d_in[7];
  const float* aw1   = (const float*)d_in[8];
  const float* aw2   = (const float*)d_in[9];

  float* ws = (float*)d_ws;
  const size_t SZ_PLANE = (size_t)BB * CC * NTOK;          // 1,179,648
  const size_t SZ_TBL = (size_t)NBH * NTOK * HDIM;         // 1,179,648 (f16 elems)
  float* yp    = ws;                                       // [B,C,N]
  float* oat   = yp + SZ_PLANE;                            // [B,N,C]
  float* stats = oat + SZ_PLANE;                           // [16*2304, 8]
  _Float16* yth = (_Float16*)(stats + (size_t)NBH * NTOK * 8);
  _Float16* ytl = yth + SZ_PLANE;
  _Float16* xh  = ytl + SZ_PLANE;
  _Float16* xl  = xh + SZ_PLANE;
  _Float16* wqh = xl + SZ_PLANE;                           // [256][256]
  _Float16* wql = wqh + CC * CC;
  _Float16* wkvh = wql + CC * CC;                          // [512][256]
  _Float16* wkvl = wkvh + 2 * CC * CC;
  _Float16* wph = wkvl + 2 * CC * CC;                      // [256][256]
  _Float16* wpl = wph + CC * CC;
  _Float16* qh  = wpl + CC * CC;                           // [16][2304][32]
  _Float16* ql  = qh + SZ_TBL;
  _Float16* kh  = ql + SZ_TBL;
  _Float16* kl  = kh + SZ_TBL;
  _Float16* vtb = kl + SZ_TBL;                             // [16][32][2304]
  _Float16* sc  = vtb + SZ_TBL;                            // [CH, N, N] f16

  const long long fixed_f = (long long)((float*)sc - ws);
  const long long avail_f = (long long)(ws_size / 4) - fixed_f;
  int CH = 4;
  while (CH > 1 && (long long)CH * NTOK * NTOK / 2 > avail_f) CH >>= 1;

  pool_kernel<<<dim3(BB * CC), 256, 0, stream>>>(y, yp);
  ln_kernel<<<dim3(NTOK / 32, BB), 256, 0, stream>>>(yp, gamma, beta, yth, ytl);
  xcast_kernel<<<dim3(NTOK / 64, CC / 64, BB), 256, 0, stream>>>(x, xh, xl);
  wtcast3_kernel<<<dim3(4 * CC), 256, 0, stream>>>(Wq, Wkv, Wproj, wqh, wql,
                                                   wkvh, wkvl, wph, wpl);
  gemm_hilo_kernel<0><<<dim3(BB * NTOK / 64, CC / 64), 256, 0, stream>>>(
      xh, xl, nullptr, wqh, wql, nullptr, qh, ql, nullptr, nullptr);
  gemm_hilo_kernel<1><<<dim3(BB * NTOK / 64, 2 * CC / 64), 256, 0, stream>>>(
      yth, ytl, nullptr, wkvh, wkvl, nullptr, kh, kl, vtb, nullptr);

  hipMemsetAsync(oat, 0, SZ_PLANE * sizeof(float), stream);

  const int nch = NBH / CH;
  for (int ch = 0; ch < nch; ++ch) {
    int bh0 = ch * CH;
    score_mfma_kernel<<<dim3(NTOK / 64, NTOK / (SMSTEP * 64), CH), 256, 0, stream>>>(
        qh, ql, kh, kl, sc, bh0);
    select_kernel<<<dim3(CH * NTOK / 4), 256, 0, stream>>>(sc, stats, aw1, aw2);
    pv_mfma_kernel<<<dim3(NTOK / 64, MSPLIT, CH), 256, 0, stream>>>(sc, vtb, stats, oat, bh0);
  }

  gemm_hilo_kernel<2><<<dim3(BB * NTOK / 64, CC / 64), 256, 0, stream>>>(
      nullptr, nullptr, oat, wph, wpl, bproj, nullptr, nullptr, nullptr, (float*)d_out);
}

// Round 18
// 280.570 us; speedup vs baseline: 1.2346x; 1.2346x over previous
//
#include <hip/hip_runtime.h>

// Problem constants
#define BB     2
#define CC     256
#define HH     48
#define WW     48
#define NTOK   2304          // H*W
#define NHEADS 8
#define HDIM   32
#define NBH    16            // BB*NHEADS
#define SCALE_QK 0.17677669529663687f  // 1/sqrt(32)
#define KSEL1  1152          // N1 // 2
#define KSEL2  768           // N1 // 3
#define NBIN   512
#define GCAP   192
#define LOSCALE 2048.0f      // 2^11: keeps f16 lo-parts in normal range

typedef _Float16 f16x8 __attribute__((ext_vector_type(8)));
typedef float f32x4 __attribute__((ext_vector_type(4)));

// Fixed-range value binning: scores ~N(0,0.1); [-1,1)/512 bins -> densest
// bin ~36 elems; clamp bins catch outliers; GCAP fallback keeps exactness.
// NOTE (r7): LDS histogram atomics must be integer (f32 atomicAdd = CAS loop).
// NOTE (r12): no per-element exp; D = bin-center approx + exact boundary.
// NOTE (r15->r16): intra-wave cross-lane LDS handoff needs explicit
// lgkmcnt(0)+sched_barrier fences (no-return atomics carry no dependency).
// NOTE (r17->r18): CH=4 REGRESSED (+42us): 576-block select dispatches =
// 2.25 blocks/CU killed latency hiding. For latency-bound kernels dispatch
// size beats cache residency. r18: CH=16 single chunk — max dispatch sizes,
// min boundaries; 203 MB hot set still mostly fits 256 MB L3.
__device__ __forceinline__ int binof(float v) {
  int b = (int)((v + 1.0f) * 256.0f);
  return min(max(b, 0), NBIN - 1);
}

// Intra-wave LDS fence: all lanes have ISSUED their DS ops (lockstep);
// drain them and forbid compiler motion across this point.
__device__ __forceinline__ void wave_lds_fence() {
  __builtin_amdgcn_sched_barrier(0);
  asm volatile("s_waitcnt lgkmcnt(0)" ::: "memory");
  __builtin_amdgcn_sched_barrier(0);
}

// ---------------------------------------------------------------------------
// Kernel A: multi-scale avg pool (3,5,7 box filters, count_include_pad) via
// per-plane integral image. One block per (b,c) plane.
__global__ __launch_bounds__(256) void pool_kernel(const float* __restrict__ y,
                                                   float* __restrict__ yp) {
  __shared__ float sp[HH * WW];
  __shared__ float I[49 * 49];
  const int bc = blockIdx.x;
  const float* src = y + (size_t)bc * (HH * WW);
  for (int i = threadIdx.x; i < HH * WW; i += 256) sp[i] = src[i];
  __syncthreads();
  if (threadIdx.x < 48) {            // row prefix sums
    int r = threadIdx.x;
    float acc = 0.f;
    I[(r + 1) * 49 + 0] = 0.f;
    for (int j = 0; j < 48; ++j) { acc += sp[r * 48 + j]; I[(r + 1) * 49 + j + 1] = acc; }
  } else if (threadIdx.x < 97) {     // zero top row
    int j = threadIdx.x - 48;
    I[j] = 0.f;
  }
  __syncthreads();
  if (threadIdx.x < 48) {            // column prefix sums
    int j = threadIdx.x + 1;
    float acc = 0.f;
    for (int i = 1; i <= 48; ++i) { acc += I[i * 49 + j]; I[i * 49 + j] = acc; }
  }
  __syncthreads();
  for (int n = threadIdx.x; n < HH * WW; n += 256) {
    int i = n / 48, j = n % 48;
    float r = 0.f;
#pragma unroll
    for (int kk = 0; kk < 3; ++kk) {
      int p = 1 + kk;                 // kernel 3,5,7 -> pad 1,2,3
      int i0 = i - p; if (i0 < 0) i0 = 0;
      int j0 = j - p; if (j0 < 0) j0 = 0;
      int i1 = i + p + 1; if (i1 > 48) i1 = 48;
      int j1 = j + p + 1; if (j1 > 48) j1 = 48;
      float s = I[i1 * 49 + j1] - I[i0 * 49 + j1] - I[i1 * 49 + j0] + I[i0 * 49 + j0];
      int k = 2 * p + 1;
      r += s / (float)(k * k);
    }
    yp[(size_t)bc * (HH * WW) + n] = r;
  }
}

// ---------------------------------------------------------------------------
// Kernel B: coalesced LayerNorm over C with LDS tile; writes f16 hi/lo.
__global__ __launch_bounds__(256) void ln_kernel(const float* __restrict__ yp,
                                                 const float* __restrict__ gamma,
                                                 const float* __restrict__ beta,
                                                 _Float16* __restrict__ yth,
                                                 _Float16* __restrict__ ytl) {
  __shared__ float tile[CC][33];
  __shared__ float part[8][32];
  __shared__ float part2[8][32];
  const int b = blockIdx.y;
  const int n0 = blockIdx.x * 32;
  const int tid = threadIdx.x;
#pragma unroll
  for (int it = 0; it < 32; ++it) {
    int idx = it * 256 + tid;
    int c = idx >> 5, nl = idx & 31;
    tile[c][nl] = yp[((size_t)(b * CC + c)) * NTOK + n0 + nl];
  }
  __syncthreads();
  const int nl = tid & 31, cs = tid >> 5;   // 8 c-slices of 32
  float s = 0.f, s2 = 0.f;
#pragma unroll
  for (int i = 0; i < 32; ++i) {
    float v = tile[cs * 32 + i][nl];
    s += v; s2 += v * v;
  }
  part[cs][nl] = s; part2[cs][nl] = s2;
  __syncthreads();
  float S = 0.f, S2 = 0.f;
#pragma unroll
  for (int i = 0; i < 8; ++i) { S += part[i][nl]; S2 += part2[i][nl]; }
  const float mean = S * (1.f / CC);
  const float var = S2 * (1.f / CC) - mean * mean;
  const float rstd = rsqrtf(var + 1e-5f);
  const size_t dstb = ((size_t)(b * NTOK + n0 + nl)) * CC + cs * 32;
#pragma unroll
  for (int g8 = 0; g8 < 4; ++g8) {
    f16x8 vh, vl;
#pragma unroll
    for (int e = 0; e < 8; ++e) {
      int c = cs * 32 + g8 * 8 + e;
      float o = (tile[c][nl] - mean) * rstd * gamma[c] + beta[c];
      _Float16 hi = (_Float16)o;
      vh[e] = hi;
      vl[e] = (_Float16)((o - (float)hi) * LOSCALE);
    }
    *(f16x8*)(yth + dstb + g8 * 8) = vh;
    *(f16x8*)(ytl + dstb + g8 * 8) = vl;
  }
}

// ---------------------------------------------------------------------------
// Kernel X: x [b][c][n] -> xh/xl [b][n][c] f16 hi/lo (LDS tile transpose).
__global__ __launch_bounds__(256) void xcast_kernel(const float* __restrict__ x,
                                                    _Float16* __restrict__ xh,
                                                    _Float16* __restrict__ xl) {
  __shared__ float tile[64][65];
  const int b = blockIdx.z;
  const int nb = blockIdx.x;   // 36 tiles of 64 n
  const int cb = blockIdx.y;   // 4 tiles of 64 c
  const int tid = threadIdx.x;
#pragma unroll
  for (int it = 0; it < 16; ++it) {
    int idx = it * 256 + tid;
    int cl = idx >> 6, nl = idx & 63;
    tile[cl][nl] = x[((size_t)(b * CC + cb * 64 + cl)) * NTOK + nb * 64 + nl];
  }
  __syncthreads();
#pragma unroll
  for (int it = 0; it < 16; ++it) {
    int idx = it * 256 + tid;
    int nl = idx >> 6, cl = idx & 63;
    float v = tile[cl][nl];
    size_t dst = ((size_t)(b * NTOK + nb * 64 + nl)) * CC + cb * 64 + cl;
    _Float16 hi = (_Float16)v;
    xh[dst] = hi;
    xl[dst] = (_Float16)((v - (float)hi) * LOSCALE);
  }
}

// ---------------------------------------------------------------------------
// Kernel W: ALL THREE weight transpose-casts in one launch.
__global__ __launch_bounds__(256) void wtcast3_kernel(
    const float* __restrict__ Wq, const float* __restrict__ Wkv,
    const float* __restrict__ Wproj,
    _Float16* __restrict__ wqh, _Float16* __restrict__ wql,
    _Float16* __restrict__ wkvh, _Float16* __restrict__ wkvl,
    _Float16* __restrict__ wph, _Float16* __restrict__ wpl) {
  const int blk = blockIdx.x;
  const int k = threadIdx.x;
  const float* W; _Float16 *wh, *wl; int ncol, col; float scale;
  if (blk < CC)            { W = Wq;    wh = wqh;  wl = wql;  ncol = CC;     col = blk;          scale = SCALE_QK; }
  else if (blk < 3 * CC)   { W = Wkv;   wh = wkvh; wl = wkvl; ncol = 2 * CC; col = blk - CC;     scale = 1.0f; }
  else                     { W = Wproj; wh = wph;  wl = wpl;  ncol = CC;     col = blk - 3 * CC; scale = 1.0f; }
  float v = W[(size_t)k * ncol + col] * scale;
  _Float16 hi = (_Float16)v;
  wh[(size_t)col * CC + k] = hi;
  wl[(size_t)col * CC + k] = (_Float16)((v - (float)hi) * LOSCALE);
}

// ---------------------------------------------------------------------------
// Kernel G: hi/lo split-precision MFMA GEMM, zero LDS (except MODE 2
// transpose epilogue). C = A[M=4608][K=256] @ B[K=256][ncol].
// MODE 0 (q):   A from Ah/Al; out -> Oh/Ol score-layout split
// MODE 1 (kv):  A from Ah/Al; col<256 -> k table; col>=256 -> vtb direct
// MODE 2 (proj): A from f32 Af (hi/lo split in-register);
//                Of[b][col][n] = out + bias[col] (LDS-transposed store)
template <int MODE>
__global__ __launch_bounds__(256) void gemm_hilo_kernel(
    const _Float16* __restrict__ Ah, const _Float16* __restrict__ Al,
    const float* __restrict__ Af,
    const _Float16* __restrict__ Bh, const _Float16* __restrict__ Bl,
    const float* __restrict__ bias,
    _Float16* __restrict__ Oh, _Float16* __restrict__ Ol,
    _Float16* __restrict__ Ov, float* __restrict__ Of) {
  const int w = threadIdx.x >> 6;
  const int lane = threadIdx.x & 63;
  const int wm = w >> 1, wc = w & 1;
  const int r16 = lane & 15, kg = lane >> 4;
  const int m0 = blockIdx.x * 64 + wm * 32;
  const int c0 = blockIdx.y * 64 + wc * 32;
  const f32x4 fz = {0.f, 0.f, 0.f, 0.f};
  f32x4 acc00 = fz, acc01 = fz, acc10 = fz, acc11 = fz;
  f32x4 ac200 = fz, ac201 = fz, ac210 = fz, ac211 = fz;
  for (int ks = 0; ks < CC; ks += 32) {
    f16x8 ah_[2], al_[2], bh_[2], bl_[2];
#pragma unroll
    for (int i = 0; i < 2; ++i) {
      size_t offa = (size_t)(m0 + i * 16 + r16) * CC + ks + kg * 8;
      if constexpr (MODE == 2) {
        f32x4 a0 = *(const f32x4*)(Af + offa);
        f32x4 a1 = *(const f32x4*)(Af + offa + 4);
#pragma unroll
        for (int e = 0; e < 4; ++e) {
          _Float16 h0 = (_Float16)a0[e];
          ah_[i][e] = h0;
          al_[i][e] = (_Float16)((a0[e] - (float)h0) * LOSCALE);
          _Float16 h1 = (_Float16)a1[e];
          ah_[i][e + 4] = h1;
          al_[i][e + 4] = (_Float16)((a1[e] - (float)h1) * LOSCALE);
        }
      } else {
        ah_[i] = *(const f16x8*)(Ah + offa);
        al_[i] = *(const f16x8*)(Al + offa);
      }
      size_t offb = (size_t)(c0 + i * 16 + r16) * CC + ks + kg * 8;
      bh_[i] = *(const f16x8*)(Bh + offb);
      bl_[i] = *(const f16x8*)(Bl + offb);
    }
    acc00 = __builtin_amdgcn_mfma_f32_16x16x32_f16(ah_[0], bh_[0], acc00, 0, 0, 0);
    ac200 = __builtin_amdgcn_mfma_f32_16x16x32_f16(ah_[0], bl_[0], ac200, 0, 0, 0);
    ac200 = __builtin_amdgcn_mfma_f32_16x16x32_f16(al_[0], bh_[0], ac200, 0, 0, 0);
    acc01 = __builtin_amdgcn_mfma_f32_16x16x32_f16(ah_[0], bh_[1], acc01, 0, 0, 0);
    ac201 = __builtin_amdgcn_mfma_f32_16x16x32_f16(ah_[0], bl_[1], ac201, 0, 0, 0);
    ac201 = __builtin_amdgcn_mfma_f32_16x16x32_f16(al_[0], bh_[1], ac201, 0, 0, 0);
    acc10 = __builtin_amdgcn_mfma_f32_16x16x32_f16(ah_[1], bh_[0], acc10, 0, 0, 0);
    ac210 = __builtin_amdgcn_mfma_f32_16x16x32_f16(ah_[1], bl_[0], ac210, 0, 0, 0);
    ac210 = __builtin_amdgcn_mfma_f32_16x16x32_f16(al_[1], bh_[0], ac210, 0, 0, 0);
    acc11 = __builtin_amdgcn_mfma_f32_16x16x32_f16(ah_[1], bh_[1], acc11, 0, 0, 0);
    ac211 = __builtin_amdgcn_mfma_f32_16x16x32_f16(ah_[1], bl_[1], ac211, 0, 0, 0);
    ac211 = __builtin_amdgcn_mfma_f32_16x16x32_f16(al_[1], bh_[1], ac211, 0, 0, 0);
  }
  f32x4 accs[2][2] = {{acc00, acc01}, {acc10, acc11}};
  f32x4 ac2s[2][2] = {{ac200, ac201}, {ac210, ac211}};
  if constexpr (MODE == 2) {
    __shared__ float ts[4][32][33];
#pragma unroll
    for (int i = 0; i < 2; ++i)
#pragma unroll
      for (int j = 0; j < 2; ++j)
#pragma unroll
        for (int r = 0; r < 4; ++r)
          ts[w][i * 16 + kg * 4 + r][j * 16 + r16] =
              accs[i][j][r] + ac2s[i][j][r] * (1.f / LOSCALE);
    __syncthreads();
    const int b = m0 / NTOK;
    const int n_base = m0 % NTOK;
#pragma unroll
    for (int t = 0; t < 16; ++t) {
      int idx = t * 64 + lane;
      int ml = idx & 31, cl = idx >> 5;
      float v = ts[w][ml][cl] + bias[c0 + cl];
      Of[((size_t)(b * CC + c0 + cl)) * NTOK + n_base + ml] = v;
    }
  } else {
#pragma unroll
    for (int i = 0; i < 2; ++i) {
#pragma unroll
      for (int j = 0; j < 2; ++j) {
#pragma unroll
        for (int r = 0; r < 4; ++r) {
          float val = accs[i][j][r] + ac2s[i][j][r] * (1.f / LOSCALE);
          int m = m0 + i * 16 + kg * 4 + r;
          int c = c0 + j * 16 + r16;
          int b = m / NTOK, n = m % NTOK;
          if (MODE == 0 || c < CC) {
            int h = (c & (CC - 1)) >> 5, d = c & 31;
            size_t dst = ((size_t)((b * 8 + h) * NTOK) + n) * HDIM + d;
            _Float16 hi = (_Float16)val;
            Oh[dst] = hi;
            Ol[dst] = (_Float16)((val - (float)hi) * LOSCALE);
          } else {
            int cc2 = c - CC;
            int h2 = cc2 >> 5, d2 = cc2 & 31;
            Ov[((size_t)((b * NHEADS + h2) * HDIM + d2)) * NTOK + n] = (_Float16)val;
          }
        }
      }
    }
  }
}

// ---------------------------------------------------------------------------
// Kernel D: scores via MFMA with f16 hi/lo split precision, stored as f16.
// Zero LDS. Wave = 32n x 32m (2x2 tiles of 16x16x32); block = 4 waves =
// 64n x 64m, m-loop x4 -> 64n x 256m.
#define SMSTEP 4
__global__ __launch_bounds__(256) void score_mfma_kernel(const _Float16* __restrict__ qh,
                                                         const _Float16* __restrict__ ql,
                                                         const _Float16* __restrict__ kh,
                                                         const _Float16* __restrict__ kl,
                                                         _Float16* __restrict__ sc, int bh0) {
  const int w = threadIdx.x >> 6;
  const int lane = threadIdx.x & 63;
  const int wn = w >> 1, wm = w & 1;
  const int r16 = lane & 15, kg = lane >> 4;
  const int z = blockIdx.z;
  const int gbh = bh0 + z;
  const size_t tb = (size_t)gbh * NTOK * HDIM;
  const int n0 = blockIdx.x * 64 + wn * 32;
  const f32x4 fz = {0.f, 0.f, 0.f, 0.f};
  f16x8 ah[2], al[2];
#pragma unroll
  for (int i = 0; i < 2; ++i) {
    size_t off = tb + (size_t)(n0 + i * 16 + r16) * HDIM + kg * 8;
    ah[i] = *(const f16x8*)(qh + off);
    al[i] = *(const f16x8*)(ql + off);
  }
  for (int s = 0; s < SMSTEP; ++s) {
    const int ms = blockIdx.y * (SMSTEP * 64) + s * 64 + wm * 32;
    f16x8 bhf[2], blf[2];
#pragma unroll
    for (int j = 0; j < 2; ++j) {
      size_t off = tb + (size_t)(ms + j * 16 + r16) * HDIM + kg * 8;
      bhf[j] = *(const f16x8*)(kh + off);
      blf[j] = *(const f16x8*)(kl + off);
    }
#pragma unroll
    for (int i = 0; i < 2; ++i)
#pragma unroll
      for (int j = 0; j < 2; ++j) {
        f32x4 acc = __builtin_amdgcn_mfma_f32_16x16x32_f16(ah[i], bhf[j], fz, 0, 0, 0);
        f32x4 ac2 = __builtin_amdgcn_mfma_f32_16x16x32_f16(ah[i], blf[j], fz, 0, 0, 0);
        ac2 = __builtin_amdgcn_mfma_f32_16x16x32_f16(al[i], bhf[j], ac2, 0, 0, 0);
        // C layout: row=(lane>>4)*4+r (q row), col=lane&15 (m col)
        size_t rowbase = ((size_t)z * NTOK + n0 + i * 16 + kg * 4) * NTOK + ms + j * 16 + r16;
#pragma unroll
        for (int r = 0; r < 4; ++r)
          sc[rowbase + (size_t)r * NTOK] = (_Float16)(acc[r] + ac2[r] * (1.0f / LOSCALE));
      }
  }
}

// ---------------------------------------------------------------------------
// Suffix-scan bucket finder over NB=NPL*64 bins: finds bucket where the
// descending cumulative count crosses krem. Writes {bucket, new_krem}.
// Wave-local; caller must fence before reading sres2.
template <int NPL>
__device__ __forceinline__ void radix_find(const unsigned* __restrict__ h,
                                           unsigned krem, unsigned* sres2) {
  const int lane = threadIdx.x & 63;
  unsigned c[NPL];
#pragma unroll
  for (int i = 0; i < NPL; ++i) c[i] = h[lane * NPL + i];
  unsigned suf[NPL];
  unsigned run = 0;
#pragma unroll
  for (int i = NPL - 1; i >= 0; --i) { run += c[i]; suf[i] = run; }
  unsigned acc = run;
#pragma unroll
  for (int off = 1; off < 64; off <<= 1) {
    unsigned t = __shfl_down(acc, off);
    if (lane + off < 64) acc += t;
  }
  unsigned tail = __shfl_down(acc, 1);
  if (lane == 63) tail = 0;
#pragma unroll
  for (int i = 0; i < NPL; ++i) {
    unsigned s = tail + suf[i];
    unsigned nx = (i + 1 < NPL) ? (tail + suf[i + 1]) : tail;
    if (s >= krem && nx < krem) {
      sres2[0] = (unsigned)(lane * NPL + i);
      sres2[1] = krem - nx;
    }
  }
}

// ---------------------------------------------------------------------------
// Kernel E (r16): WAVE-PER-ROW select with explicit intra-wave LDS fences.
// Block = 4 waves = 4 rows; zero __syncthreads.
__global__ __launch_bounds__(256) void select_kernel(const _Float16* __restrict__ sc,
                                                     float* __restrict__ stats,
                                                     const float* __restrict__ w1p,
                                                     const float* __restrict__ w2p) {
  __shared__ unsigned cnt[4][NBIN];
  __shared__ float buf[4][2][GCAP];
  __shared__ unsigned bcnt[4][2];
  __shared__ unsigned sres[4][4];
  __shared__ float tthr[4][2];
  const int tid = threadIdx.x;
  const int wv = tid >> 6, lane = tid & 63;
  const int row = blockIdx.x * 4 + wv;
  const size_t base = (size_t)row * NTOK;
  unsigned* mycnt = cnt[wv];
#pragma unroll
  for (int i = 0; i < NBIN / 64; ++i) mycnt[lane * (NBIN / 64) + i] = 0u;
  if (lane < 2) bcnt[wv][lane] = 0u;
  wave_lds_fence();                       // zeroing visible before atomics
  // load row into registers: 288 f16x8 groups; 4/lane + 1 extra for lane<32
  f16x8 r[4];
#pragma unroll
  for (int j = 0; j < 4; ++j) r[j] = *((const f16x8*)(sc + base) + j * 64 + lane);
  const bool two = (lane < 32);
  f16x8 r4 = two ? *((const f16x8*)(sc + base) + 256 + lane) : f16x8{};
  // count histogram (u32 LDS atomics, wave-private region)
#pragma unroll
  for (int j = 0; j < 4; ++j)
#pragma unroll
    for (int e = 0; e < 8; ++e) atomicAdd(&mycnt[binof((float)r[j][e])], 1u);
  if (two) {
#pragma unroll
    for (int e = 0; e < 8; ++e) atomicAdd(&mycnt[binof((float)r4[e])], 1u);
  }
  wave_lds_fence();                       // histogram visible before reads
  // both selections' boundary buckets
  radix_find<NBIN / 64>(mycnt, KSEL1, &sres[wv][0]);
  radix_find<NBIN / 64>(mycnt, KSEL2, &sres[wv][2]);
  wave_lds_fence();                       // sres visible to all lanes
  const int b1 = (int)sres[wv][0], b2 = (int)sres[wv][2];
  const unsigned k1 = sres[wv][1], k2 = sres[wv][3];
  const unsigned c1 = mycnt[b1], c2 = mycnt[b2];
  const bool g1ok = (c1 <= GCAP), g2ok = (c2 <= GCAP);
  const float lo1 = (b1 == 0) ? -3.4e38f : ((float)b1 * (1.f / 256.f) - 1.f);
  const float hi1 = (b1 == NBIN - 1) ? 3.4e38f : ((float)(b1 + 1) * (1.f / 256.f) - 1.f);
  const float lo2 = (b2 == 0) ? -3.4e38f : ((float)b2 * (1.f / 256.f) - 1.f);
  const float hi2 = (b2 == NBIN - 1) ? 3.4e38f : ((float)(b2 + 1) * (1.f / 256.f) - 1.f);
  // gather boundary-bucket elements from registers
#pragma unroll
  for (int j = 0; j < 4; ++j)
#pragma unroll
    for (int e = 0; e < 8; ++e) {
      float v = (float)r[j][e];
      if (g1ok && v >= lo1 && v < hi1) buf[wv][0][atomicAdd(&bcnt[wv][0], 1u)] = v;
      if (g2ok && v >= lo2 && v < hi2) buf[wv][1][atomicAdd(&bcnt[wv][1], 1u)] = v;
    }
  if (two) {
#pragma unroll
    for (int e = 0; e < 8; ++e) {
      float v = (float)r4[e];
      if (g1ok && v >= lo1 && v < hi1) buf[wv][0][atomicAdd(&bcnt[wv][0], 1u)] = v;
      if (g2ok && v >= lo2 && v < hi2) buf[wv][1][atomicAdd(&bcnt[wv][1], 1u)] = v;
    }
  }
  wave_lds_fence();                       // gathered buf visible
  // exact k-th within boundary bucket (both sels, serial per wave)
#pragma unroll
  for (int sel = 0; sel < 2; ++sel) {
    const unsigned kk = sel ? k2 : k1;
    const int bb = sel ? b2 : b1;
    const unsigned cc = sel ? c2 : c1;
    if (cc <= GCAP) {
      for (unsigned i = lane; i < cc; i += 64) {
        float xv = buf[wv][sel][i];
        unsigned g = 0, m = 0;
        for (unsigned j2 = 0; j2 < cc; ++j2) {
          float yv = buf[wv][sel][j2];   // same-address broadcast
          g += (yv > xv) ? 1u : 0u;
          m += (yv == xv) ? 1u : 0u;
        }
        if (g < kk && kk <= g + m) tthr[wv][sel] = xv;
      }
    } else {
      // exact fallback: re-read row from global (degenerate data only)
      for (int i = lane; i < NTOK; i += 64) {
        float xv = (float)sc[base + i];
        if (binof(xv) != bb) continue;
        unsigned g = 0, m = 0;
        for (int j2 = 0; j2 < NTOK; ++j2) {
          float yv = (float)sc[base + j2];
          if (binof(yv) != bb) continue;
          g += (yv > xv) ? 1u : 0u;
          m += (yv == xv) ? 1u : 0u;
        }
        if (g < kk && kk <= g + m) tthr[wv][sel] = xv;
      }
    }
  }
  wave_lds_fence();                       // tthr visible
  // D = suffix of cnt[b]*exp(center_b) + exact boundary partial (both sels)
  float D[2];
#pragma unroll
  for (int sel = 0; sel < 2; ++sel) {
    const int bb = sel ? b2 : b1;
    const unsigned cc = sel ? c2 : c1;
    const float t = tthr[wv][sel];
    float ps = 0.f;
    if (cc <= GCAP) {
      for (unsigned i = lane; i < cc; i += 64) {
        float xv = buf[wv][sel][i];
        if (xv >= t) ps += __expf(xv);
      }
    } else {
      for (int i = lane; i < NTOK; i += 64) {
        float xv = (float)sc[base + i];
        if (binof(xv) == bb && xv >= t) ps += __expf(xv);
      }
    }
    for (int b = bb + 1 + lane; b < NBIN; b += 64)
      ps += (float)mycnt[b] * __expf((float)b * (1.f / 256.f) + (0.5f / 256.f) - 1.f);
#pragma unroll
    for (int off = 32; off; off >>= 1) ps += __shfl_down(ps, off);
    D[sel] = ps;
  }
  if (lane == 0) {
    float* st = stats + (size_t)row * 8;
    st[0] = 0.f;
    st[1] = tthr[wv][0];
    st[2] = tthr[wv][1];
    st[3] = w1p[0] / D[0];
    st[4] = w2p[0] / D[1];
  }
}

// ---------------------------------------------------------------------------
// Kernel F: PV via MFMA, zero LDS. Wave w of each block owns a 16(n) x 32(d)
// output tile. m-split over blockIdx.y, atomicAdd combine into zeroed oat.
#define MSPLIT 4
__global__ __launch_bounds__(256) void pv_mfma_kernel(const _Float16* __restrict__ sc,
                                                      const _Float16* __restrict__ vtb,
                                                      const float* __restrict__ stats,
                                                      float* __restrict__ oat, int bh0) {
  const int w = threadIdx.x >> 6;
  const int l = threadIdx.x & 63;
  const int z = blockIdx.z;
  const int gbh = bh0 + z;
  const int b = gbh >> 3, h = gbh & 7;
  const int n0 = blockIdx.x * 64 + w * 16;
  const int row = l & 15;            // A row / C col (d within half)
  const int kg = l >> 4;             // k-group
  const int n = n0 + row;
  const float* st = stats + ((size_t)z * NTOK + n) * 8;
  const float mx = st[0], t1 = st[1], t2 = st[2], w1d = st[3], w2d = st[4];
  const _Float16* srow = sc + ((size_t)z * NTOK + n) * NTOK;
  const _Float16* v0 = vtb + ((size_t)gbh * HDIM + row) * NTOK;
  const _Float16* v1 = v0 + 16 * NTOK;
  f32x4 acc0 = {0.f, 0.f, 0.f, 0.f};
  f32x4 acc1 = {0.f, 0.f, 0.f, 0.f};
  const int msteps = (NTOK / 32) / MSPLIT;   // 18
  int m0 = blockIdx.y * msteps * 32 + kg * 8;
#pragma unroll 2
  for (int s = 0; s < msteps; ++s, m0 += 32) {
    f16x8 sv8 = *(const f16x8*)(srow + m0);
    f16x8 afr;
#pragma unroll
    for (int i = 0; i < 8; ++i) {
      float sv = (float)sv8[i];
      float e = __expf(sv - mx);
      float wgt = (sv >= t1 ? w1d : 0.f) + (sv >= t2 ? w2d : 0.f);
      afr[i] = (_Float16)(e * wgt);
    }
    f16x8 bfr0 = *(const f16x8*)(v0 + m0);
    f16x8 bfr1 = *(const f16x8*)(v1 + m0);
    acc0 = __builtin_amdgcn_mfma_f32_16x16x32_f16(afr, bfr0, acc0, 0, 0, 0);
    acc1 = __builtin_amdgcn_mfma_f32_16x16x32_f16(afr, bfr1, acc1, 0, 0, 0);
  }
  // C/D layout: col = lane&15 (=row var), row = (lane>>4)*4 + reg
#pragma unroll
  for (int r = 0; r < 4; ++r) {
    int nn = n0 + kg * 4 + r;
    float* dst = &oat[((size_t)(b * NTOK + nn)) * CC + h * HDIM];
    atomicAdd(&dst[row], acc0[r]);
    atomicAdd(&dst[16 + row], acc1[r]);
  }
}

// ---------------------------------------------------------------------------
extern "C" void kernel_launch(void* const* d_in, const int* in_sizes, int n_in,
                              void* d_out, int out_size, void* d_ws, size_t ws_size,
                              hipStream_t stream) {
  const float* x     = (const float*)d_in[0];
  const float* y     = (const float*)d_in[1];
  const float* Wq    = (const float*)d_in[2];
  const float* Wkv   = (const float*)d_in[3];
  const float* Wproj = (const float*)d_in[4];
  const float* bproj = (const float*)d_in[5];
  const float* gamma = (const float*)d_in[6];
  const float* beta  = (const float*)d_in[7];
  const float* aw1   = (const float*)d_in[8];
  const float* aw2   = (const float*)d_in[9];

  float* ws = (float*)d_ws;
  const size_t SZ_PLANE = (size_t)BB * CC * NTOK;          // 1,179,648
  const size_t SZ_TBL = (size_t)NBH * NTOK * HDIM;         // 1,179,648 (f16 elems)
  float* yp    = ws;                                       // [B,C,N]
  float* oat   = yp + SZ_PLANE;                            // [B,N,C]
  float* stats = oat + SZ_PLANE;                           // [16*2304, 8]
  _Float16* yth = (_Float16*)(stats + (size_t)NBH * NTOK * 8);
  _Float16* ytl = yth + SZ_PLANE;
  _Float16* xh  = ytl + SZ_PLANE;
  _Float16* xl  = xh + SZ_PLANE;
  _Float16* wqh = xl + SZ_PLANE;                           // [256][256]
  _Float16* wql = wqh + CC * CC;
  _Float16* wkvh = wql + CC * CC;                          // [512][256]
  _Float16* wkvl = wkvh + 2 * CC * CC;
  _Float16* wph = wkvl + 2 * CC * CC;                      // [256][256]
  _Float16* wpl = wph + CC * CC;
  _Float16* qh  = wpl + CC * CC;                           // [16][2304][32]
  _Float16* ql  = qh + SZ_TBL;
  _Float16* kh  = ql + SZ_TBL;
  _Float16* kl  = kh + SZ_TBL;
  _Float16* vtb = kl + SZ_TBL;                             // [16][32][2304]
  _Float16* sc  = vtb + SZ_TBL;                            // [CH, N, N] f16

  const long long fixed_f = (long long)((float*)sc - ws);
  const long long avail_f = (long long)(ws_size / 4) - fixed_f;
  int CH = 16;
  while (CH > 1 && (long long)CH * NTOK * NTOK / 2 > avail_f) CH >>= 1;

  pool_kernel<<<dim3(BB * CC), 256, 0, stream>>>(y, yp);
  ln_kernel<<<dim3(NTOK / 32, BB), 256, 0, stream>>>(yp, gamma, beta, yth, ytl);
  xcast_kernel<<<dim3(NTOK / 64, CC / 64, BB), 256, 0, stream>>>(x, xh, xl);
  wtcast3_kernel<<<dim3(4 * CC), 256, 0, stream>>>(Wq, Wkv, Wproj, wqh, wql,
                                                   wkvh, wkvl, wph, wpl);
  gemm_hilo_kernel<0><<<dim3(BB * NTOK / 64, CC / 64), 256, 0, stream>>>(
      xh, xl, nullptr, wqh, wql, nullptr, qh, ql, nullptr, nullptr);
  gemm_hilo_kernel<1><<<dim3(BB * NTOK / 64, 2 * CC / 64), 256, 0, stream>>>(
      yth, ytl, nullptr, wkvh, wkvl, nullptr, kh, kl, vtb, nullptr);

  hipMemsetAsync(oat, 0, SZ_PLANE * sizeof(float), stream);

  const int nch = NBH / CH;
  for (int ch = 0; ch < nch; ++ch) {
    int bh0 = ch * CH;
    score_mfma_kernel<<<dim3(NTOK / 64, NTOK / (SMSTEP * 64), CH), 256, 0, stream>>>(
        qh, ql, kh, kl, sc, bh0);
    select_kernel<<<dim3(CH * NTOK / 4), 256, 0, stream>>>(sc, stats, aw1, aw2);
    pv_mfma_kernel<<<dim3(NTOK / 64, MSPLIT, CH), 256, 0, stream>>>(sc, vtb, stats, oat, bh0);
  }

  gemm_hilo_kernel<2><<<dim3(BB * NTOK / 64, CC / 64), 256, 0, stream>>>(
      nullptr, nullptr, oat, wph, wpl, bproj, nullptr, nullptr, nullptr, (float*)d_out);
}

// Round 20
// 280.270 us; speedup vs baseline: 1.2359x; 1.0011x over previous
//
#include <hip/hip_runtime.h>

// Problem constants
#define BB     2
#define CC     256
#define HH     48
#define WW     48
#define NTOK   2304          // H*W
#define NHEADS 8
#define HDIM   32
#define NBH    16            // BB*NHEADS
#define SCALE_QK 0.17677669529663687f  // 1/sqrt(32)
#define KSEL1  1152          // N1 // 2
#define KSEL2  768           // N1 // 3
#define NBIN   512
#define GCAP   192
#define LOSCALE 2048.0f      // 2^11: keeps f16 lo-parts in normal range

typedef _Float16 f16x8 __attribute__((ext_vector_type(8)));
typedef float f32x4 __attribute__((ext_vector_type(4)));

// Fixed-range value binning: scores ~N(0,0.1); [-1,1)/512 bins -> densest
// bin ~36 elems; clamp bins catch outliers; GCAP fallback keeps exactness.
// NOTE (r7): LDS histogram atomics must be integer (f32 atomicAdd = CAS loop).
// NOTE (r12): no per-element exp; D = bin-center approx + exact boundary.
// NOTE (r15->r16): intra-wave cross-lane LDS handoff needs explicit
// lgkmcnt(0)+sched_barrier fences (no-return atomics carry no dependency).
// NOTE (r17->r18): for latency-bound kernels dispatch size beats cache
// residency: CH=16 single chunk.
// NOTE (r19 FAILURE -> r20 revert): packed-f16 bins ((v+1h)*256h) are NOT
// edge-consistent: v+1 in f16 has ulp 2^-10 near 1.0, shifting effective
// bin edges by up to 2^-11 (~1/8 bin). Histogram (rounded map) and gather
// (true f16 edges) partitioned the row differently -> wrong thresholds.
// All phases MUST share one bin map; reverted to f32 binof everywhere.
__device__ __forceinline__ int binof(float v) {
  int b = (int)((v + 1.0f) * 256.0f);
  return min(max(b, 0), NBIN - 1);
}

// Intra-wave LDS fence: all lanes have ISSUED their DS ops (lockstep);
// drain them and forbid compiler motion across this point.
__device__ __forceinline__ void wave_lds_fence() {
  __builtin_amdgcn_sched_barrier(0);
  asm volatile("s_waitcnt lgkmcnt(0)" ::: "memory");
  __builtin_amdgcn_sched_barrier(0);
}

// ---------------------------------------------------------------------------
// Kernel A: multi-scale avg pool (3,5,7 box filters, count_include_pad) via
// per-plane integral image. One block per (b,c) plane.
__global__ __launch_bounds__(256) void pool_kernel(const float* __restrict__ y,
                                                   float* __restrict__ yp) {
  __shared__ float sp[HH * WW];
  __shared__ float I[49 * 49];
  const int bc = blockIdx.x;
  const float* src = y + (size_t)bc * (HH * WW);
  for (int i = threadIdx.x; i < HH * WW; i += 256) sp[i] = src[i];
  __syncthreads();
  if (threadIdx.x < 48) {            // row prefix sums
    int r = threadIdx.x;
    float acc = 0.f;
    I[(r + 1) * 49 + 0] = 0.f;
    for (int j = 0; j < 48; ++j) { acc += sp[r * 48 + j]; I[(r + 1) * 49 + j + 1] = acc; }
  } else if (threadIdx.x < 97) {     // zero top row
    int j = threadIdx.x - 48;
    I[j] = 0.f;
  }
  __syncthreads();
  if (threadIdx.x < 48) {            // column prefix sums
    int j = threadIdx.x + 1;
    float acc = 0.f;
    for (int i = 1; i <= 48; ++i) { acc += I[i * 49 + j]; I[i * 49 + j] = acc; }
  }
  __syncthreads();
  for (int n = threadIdx.x; n < HH * WW; n += 256) {
    int i = n / 48, j = n % 48;
    float r = 0.f;
#pragma unroll
    for (int kk = 0; kk < 3; ++kk) {
      int p = 1 + kk;                 // kernel 3,5,7 -> pad 1,2,3
      int i0 = i - p; if (i0 < 0) i0 = 0;
      int j0 = j - p; if (j0 < 0) j0 = 0;
      int i1 = i + p + 1; if (i1 > 48) i1 = 48;
      int j1 = j + p + 1; if (j1 > 48) j1 = 48;
      float s = I[i1 * 49 + j1] - I[i0 * 49 + j1] - I[i1 * 49 + j0] + I[i0 * 49 + j0];
      int k = 2 * p + 1;
      r += s / (float)(k * k);
    }
    yp[(size_t)bc * (HH * WW) + n] = r;
  }
}

// ---------------------------------------------------------------------------
// Kernel B: coalesced LayerNorm over C with LDS tile; writes f16 hi/lo.
__global__ __launch_bounds__(256) void ln_kernel(const float* __restrict__ yp,
                                                 const float* __restrict__ gamma,
                                                 const float* __restrict__ beta,
                                                 _Float16* __restrict__ yth,
                                                 _Float16* __restrict__ ytl) {
  __shared__ float tile[CC][33];
  __shared__ float part[8][32];
  __shared__ float part2[8][32];
  const int b = blockIdx.y;
  const int n0 = blockIdx.x * 32;
  const int tid = threadIdx.x;
#pragma unroll
  for (int it = 0; it < 32; ++it) {
    int idx = it * 256 + tid;
    int c = idx >> 5, nl = idx & 31;
    tile[c][nl] = yp[((size_t)(b * CC + c)) * NTOK + n0 + nl];
  }
  __syncthreads();
  const int nl = tid & 31, cs = tid >> 5;   // 8 c-slices of 32
  float s = 0.f, s2 = 0.f;
#pragma unroll
  for (int i = 0; i < 32; ++i) {
    float v = tile[cs * 32 + i][nl];
    s += v; s2 += v * v;
  }
  part[cs][nl] = s; part2[cs][nl] = s2;
  __syncthreads();
  float S = 0.f, S2 = 0.f;
#pragma unroll
  for (int i = 0; i < 8; ++i) { S += part[i][nl]; S2 += part2[i][nl]; }
  const float mean = S * (1.f / CC);
  const float var = S2 * (1.f / CC) - mean * mean;
  const float rstd = rsqrtf(var + 1e-5f);
  const size_t dstb = ((size_t)(b * NTOK + n0 + nl)) * CC + cs * 32;
#pragma unroll
  for (int g8 = 0; g8 < 4; ++g8) {
    f16x8 vh, vl;
#pragma unroll
    for (int e = 0; e < 8; ++e) {
      int c = cs * 32 + g8 * 8 + e;
      float o = (tile[c][nl] - mean) * rstd * gamma[c] + beta[c];
      _Float16 hi = (_Float16)o;
      vh[e] = hi;
      vl[e] = (_Float16)((o - (float)hi) * LOSCALE);
    }
    *(f16x8*)(yth + dstb + g8 * 8) = vh;
    *(f16x8*)(ytl + dstb + g8 * 8) = vl;
  }
}

// ---------------------------------------------------------------------------
// Kernel X: x [b][c][n] -> xh/xl [b][n][c] f16 hi/lo (LDS tile transpose).
__global__ __launch_bounds__(256) void xcast_kernel(const float* __restrict__ x,
                                                    _Float16* __restrict__ xh,
                                                    _Float16* __restrict__ xl) {
  __shared__ float tile[64][65];
  const int b = blockIdx.z;
  const int nb = blockIdx.x;   // 36 tiles of 64 n
  const int cb = blockIdx.y;   // 4 tiles of 64 c
  const int tid = threadIdx.x;
#pragma unroll
  for (int it = 0; it < 16; ++it) {
    int idx = it * 256 + tid;
    int cl = idx >> 6, nl = idx & 63;
    tile[cl][nl] = x[((size_t)(b * CC + cb * 64 + cl)) * NTOK + nb * 64 + nl];
  }
  __syncthreads();
#pragma unroll
  for (int it = 0; it < 16; ++it) {
    int idx = it * 256 + tid;
    int nl = idx >> 6, cl = idx & 63;
    float v = tile[cl][nl];
    size_t dst = ((size_t)(b * NTOK + nb * 64 + nl)) * CC + cb * 64 + cl;
    _Float16 hi = (_Float16)v;
    xh[dst] = hi;
    xl[dst] = (_Float16)((v - (float)hi) * LOSCALE);
  }
}

// ---------------------------------------------------------------------------
// Kernel W: ALL THREE weight transpose-casts in one launch.
__global__ __launch_bounds__(256) void wtcast3_kernel(
    const float* __restrict__ Wq, const float* __restrict__ Wkv,
    const float* __restrict__ Wproj,
    _Float16* __restrict__ wqh, _Float16* __restrict__ wql,
    _Float16* __restrict__ wkvh, _Float16* __restrict__ wkvl,
    _Float16* __restrict__ wph, _Float16* __restrict__ wpl) {
  const int blk = blockIdx.x;
  const int k = threadIdx.x;
  const float* W; _Float16 *wh, *wl; int ncol, col; float scale;
  if (blk < CC)            { W = Wq;    wh = wqh;  wl = wql;  ncol = CC;     col = blk;          scale = SCALE_QK; }
  else if (blk < 3 * CC)   { W = Wkv;   wh = wkvh; wl = wkvl; ncol = 2 * CC; col = blk - CC;     scale = 1.0f; }
  else                     { W = Wproj; wh = wph;  wl = wpl;  ncol = CC;     col = blk - 3 * CC; scale = 1.0f; }
  float v = W[(size_t)k * ncol + col] * scale;
  _Float16 hi = (_Float16)v;
  wh[(size_t)col * CC + k] = hi;
  wl[(size_t)col * CC + k] = (_Float16)((v - (float)hi) * LOSCALE);
}

// ---------------------------------------------------------------------------
// Kernel G: hi/lo split-precision MFMA GEMM, zero LDS (except MODE 2
// transpose epilogue). C = A[M=4608][K=256] @ B[K=256][ncol].
// MODE 0 (q):   A from Ah/Al; out -> Oh/Ol score-layout split
// MODE 1 (kv):  A from Ah/Al; col<256 -> k table; col>=256 -> vtb direct
// MODE 2 (proj): A from f32 Af (hi/lo split in-register);
//                Of[b][col][n] = out + bias[col] (LDS-transposed store)
template <int MODE>
__global__ __launch_bounds__(256) void gemm_hilo_kernel(
    const _Float16* __restrict__ Ah, const _Float16* __restrict__ Al,
    const float* __restrict__ Af,
    const _Float16* __restrict__ Bh, const _Float16* __restrict__ Bl,
    const float* __restrict__ bias,
    _Float16* __restrict__ Oh, _Float16* __restrict__ Ol,
    _Float16* __restrict__ Ov, float* __restrict__ Of) {
  const int w = threadIdx.x >> 6;
  const int lane = threadIdx.x & 63;
  const int wm = w >> 1, wc = w & 1;
  const int r16 = lane & 15, kg = lane >> 4;
  const int m0 = blockIdx.x * 64 + wm * 32;
  const int c0 = blockIdx.y * 64 + wc * 32;
  const f32x4 fz = {0.f, 0.f, 0.f, 0.f};
  f32x4 acc00 = fz, acc01 = fz, acc10 = fz, acc11 = fz;
  f32x4 ac200 = fz, ac201 = fz, ac210 = fz, ac211 = fz;
  for (int ks = 0; ks < CC; ks += 32) {
    f16x8 ah_[2], al_[2], bh_[2], bl_[2];
#pragma unroll
    for (int i = 0; i < 2; ++i) {
      size_t offa = (size_t)(m0 + i * 16 + r16) * CC + ks + kg * 8;
      if constexpr (MODE == 2) {
        f32x4 a0 = *(const f32x4*)(Af + offa);
        f32x4 a1 = *(const f32x4*)(Af + offa + 4);
#pragma unroll
        for (int e = 0; e < 4; ++e) {
          _Float16 h0 = (_Float16)a0[e];
          ah_[i][e] = h0;
          al_[i][e] = (_Float16)((a0[e] - (float)h0) * LOSCALE);
          _Float16 h1 = (_Float16)a1[e];
          ah_[i][e + 4] = h1;
          al_[i][e + 4] = (_Float16)((a1[e] - (float)h1) * LOSCALE);
        }
      } else {
        ah_[i] = *(const f16x8*)(Ah + offa);
        al_[i] = *(const f16x8*)(Al + offa);
      }
      size_t offb = (size_t)(c0 + i * 16 + r16) * CC + ks + kg * 8;
      bh_[i] = *(const f16x8*)(Bh + offb);
      bl_[i] = *(const f16x8*)(Bl + offb);
    }
    acc00 = __builtin_amdgcn_mfma_f32_16x16x32_f16(ah_[0], bh_[0], acc00, 0, 0, 0);
    ac200 = __builtin_amdgcn_mfma_f32_16x16x32_f16(ah_[0], bl_[0], ac200, 0, 0, 0);
    ac200 = __builtin_amdgcn_mfma_f32_16x16x32_f16(al_[0], bh_[0], ac200, 0, 0, 0);
    acc01 = __builtin_amdgcn_mfma_f32_16x16x32_f16(ah_[0], bh_[1], acc01, 0, 0, 0);
    ac201 = __builtin_amdgcn_mfma_f32_16x16x32_f16(ah_[0], bl_[1], ac201, 0, 0, 0);
    ac201 = __builtin_amdgcn_mfma_f32_16x16x32_f16(al_[0], bh_[1], ac201, 0, 0, 0);
    acc10 = __builtin_amdgcn_mfma_f32_16x16x32_f16(ah_[1], bh_[0], acc10, 0, 0, 0);
    ac210 = __builtin_amdgcn_mfma_f32_16x16x32_f16(ah_[1], bl_[0], ac210, 0, 0, 0);
    ac210 = __builtin_amdgcn_mfma_f32_16x16x32_f16(al_[1], bh_[0], ac210, 0, 0, 0);
    acc11 = __builtin_amdgcn_mfma_f32_16x16x32_f16(ah_[1], bh_[1], acc11, 0, 0, 0);
    ac211 = __builtin_amdgcn_mfma_f32_16x16x32_f16(ah_[1], bl_[1], ac211, 0, 0, 0);
    ac211 = __builtin_amdgcn_mfma_f32_16x16x32_f16(al_[1], bh_[1], ac211, 0, 0, 0);
  }
  f32x4 accs[2][2] = {{acc00, acc01}, {acc10, acc11}};
  f32x4 ac2s[2][2] = {{ac200, ac201}, {ac210, ac211}};
  if constexpr (MODE == 2) {
    __shared__ float ts[4][32][33];
#pragma unroll
    for (int i = 0; i < 2; ++i)
#pragma unroll
      for (int j = 0; j < 2; ++j)
#pragma unroll
        for (int r = 0; r < 4; ++r)
          ts[w][i * 16 + kg * 4 + r][j * 16 + r16] =
              accs[i][j][r] + ac2s[i][j][r] * (1.f / LOSCALE);
    __syncthreads();
    const int b = m0 / NTOK;
    const int n_base = m0 % NTOK;
#pragma unroll
    for (int t = 0; t < 16; ++t) {
      int idx = t * 64 + lane;
      int ml = idx & 31, cl = idx >> 5;
      float v = ts[w][ml][cl] + bias[c0 + cl];
      Of[((size_t)(b * CC + c0 + cl)) * NTOK + n_base + ml] = v;
    }
  } else {
#pragma unroll
    for (int i = 0; i < 2; ++i) {
#pragma unroll
      for (int j = 0; j < 2; ++j) {
#pragma unroll
        for (int r = 0; r < 4; ++r) {
          float val = accs[i][j][r] + ac2s[i][j][r] * (1.f / LOSCALE);
          int m = m0 + i * 16 + kg * 4 + r;
          int c = c0 + j * 16 + r16;
          int b = m / NTOK, n = m % NTOK;
          if (MODE == 0 || c < CC) {
            int h = (c & (CC - 1)) >> 5, d = c & 31;
            size_t dst = ((size_t)((b * 8 + h) * NTOK) + n) * HDIM + d;
            _Float16 hi = (_Float16)val;
            Oh[dst] = hi;
            Ol[dst] = (_Float16)((val - (float)hi) * LOSCALE);
          } else {
            int cc2 = c - CC;
            int h2 = cc2 >> 5, d2 = cc2 & 31;
            Ov[((size_t)((b * NHEADS + h2) * HDIM + d2)) * NTOK + n] = (_Float16)val;
          }
        }
      }
    }
  }
}

// ---------------------------------------------------------------------------
// Kernel D: scores via MFMA with f16 hi/lo split precision, stored as f16.
// Zero LDS. Wave = 32n x 32m (2x2 tiles of 16x16x32); block = 4 waves =
// 64n x 64m, m-loop x4 -> 64n x 256m.
#define SMSTEP 4
__global__ __launch_bounds__(256) void score_mfma_kernel(const _Float16* __restrict__ qh,
                                                         const _Float16* __restrict__ ql,
                                                         const _Float16* __restrict__ kh,
                                                         const _Float16* __restrict__ kl,
                                                         _Float16* __restrict__ sc, int bh0) {
  const int w = threadIdx.x >> 6;
  const int lane = threadIdx.x & 63;
  const int wn = w >> 1, wm = w & 1;
  const int r16 = lane & 15, kg = lane >> 4;
  const int z = blockIdx.z;
  const int gbh = bh0 + z;
  const size_t tb = (size_t)gbh * NTOK * HDIM;
  const int n0 = blockIdx.x * 64 + wn * 32;
  const f32x4 fz = {0.f, 0.f, 0.f, 0.f};
  f16x8 ah[2], al[2];
#pragma unroll
  for (int i = 0; i < 2; ++i) {
    size_t off = tb + (size_t)(n0 + i * 16 + r16) * HDIM + kg * 8;
    ah[i] = *(const f16x8*)(qh + off);
    al[i] = *(const f16x8*)(ql + off);
  }
  for (int s = 0; s < SMSTEP; ++s) {
    const int ms = blockIdx.y * (SMSTEP * 64) + s * 64 + wm * 32;
    f16x8 bhf[2], blf[2];
#pragma unroll
    for (int j = 0; j < 2; ++j) {
      size_t off = tb + (size_t)(ms + j * 16 + r16) * HDIM + kg * 8;
      bhf[j] = *(const f16x8*)(kh + off);
      blf[j] = *(const f16x8*)(kl + off);
    }
#pragma unroll
    for (int i = 0; i < 2; ++i)
#pragma unroll
      for (int j = 0; j < 2; ++j) {
        f32x4 acc = __builtin_amdgcn_mfma_f32_16x16x32_f16(ah[i], bhf[j], fz, 0, 0, 0);
        f32x4 ac2 = __builtin_amdgcn_mfma_f32_16x16x32_f16(ah[i], blf[j], fz, 0, 0, 0);
        ac2 = __builtin_amdgcn_mfma_f32_16x16x32_f16(al[i], bhf[j], ac2, 0, 0, 0);
        // C layout: row=(lane>>4)*4+r (q row), col=lane&15 (m col)
        size_t rowbase = ((size_t)z * NTOK + n0 + i * 16 + kg * 4) * NTOK + ms + j * 16 + r16;
#pragma unroll
        for (int r = 0; r < 4; ++r)
          sc[rowbase + (size_t)r * NTOK] = (_Float16)(acc[r] + ac2[r] * (1.0f / LOSCALE));
      }
  }
}

// ---------------------------------------------------------------------------
// Suffix-scan bucket finder over NB=NPL*64 bins: finds bucket where the
// descending cumulative count crosses krem. Writes {bucket, new_krem}.
// Wave-local; caller must fence before reading sres2.
template <int NPL>
__device__ __forceinline__ void radix_find(const unsigned* __restrict__ h,
                                           unsigned krem, unsigned* sres2) {
  const int lane = threadIdx.x & 63;
  unsigned c[NPL];
#pragma unroll
  for (int i = 0; i < NPL; ++i) c[i] = h[lane * NPL + i];
  unsigned suf[NPL];
  unsigned run = 0;
#pragma unroll
  for (int i = NPL - 1; i >= 0; --i) { run += c[i]; suf[i] = run; }
  unsigned acc = run;
#pragma unroll
  for (int off = 1; off < 64; off <<= 1) {
    unsigned t = __shfl_down(acc, off);
    if (lane + off < 64) acc += t;
  }
  unsigned tail = __shfl_down(acc, 1);
  if (lane == 63) tail = 0;
#pragma unroll
  for (int i = 0; i < NPL; ++i) {
    unsigned s = tail + suf[i];
    unsigned nx = (i + 1 < NPL) ? (tail + suf[i + 1]) : tail;
    if (s >= krem && nx < krem) {
      sres2[0] = (unsigned)(lane * NPL + i);
      sres2[1] = krem - nx;
    }
  }
}

// ---------------------------------------------------------------------------
// Kernel E (r16/r18): WAVE-PER-ROW select with explicit intra-wave LDS
// fences. Block = 4 waves = 4 rows; zero __syncthreads. One f32 bin map
// (binof) shared by ALL phases.
__global__ __launch_bounds__(256) void select_kernel(const _Float16* __restrict__ sc,
                                                     float* __restrict__ stats,
                                                     const float* __restrict__ w1p,
                                                     const float* __restrict__ w2p) {
  __shared__ unsigned cnt[4][NBIN];
  __shared__ float buf[4][2][GCAP];
  __shared__ unsigned bcnt[4][2];
  __shared__ unsigned sres[4][4];
  __shared__ float tthr[4][2];
  const int tid = threadIdx.x;
  const int wv = tid >> 6, lane = tid & 63;
  const int row = blockIdx.x * 4 + wv;
  const size_t base = (size_t)row * NTOK;
  unsigned* mycnt = cnt[wv];
#pragma unroll
  for (int i = 0; i < NBIN / 64; ++i) mycnt[lane * (NBIN / 64) + i] = 0u;
  if (lane < 2) bcnt[wv][lane] = 0u;
  wave_lds_fence();                       // zeroing visible before atomics
  // load row into registers: 288 f16x8 groups; 4/lane + 1 extra for lane<32
  f16x8 r[4];
#pragma unroll
  for (int j = 0; j < 4; ++j) r[j] = *((const f16x8*)(sc + base) + j * 64 + lane);
  const bool two = (lane < 32);
  f16x8 r4 = two ? *((const f16x8*)(sc + base) + 256 + lane) : f16x8{};
  // count histogram (u32 LDS atomics, wave-private region)
#pragma unroll
  for (int j = 0; j < 4; ++j)
#pragma unroll
    for (int e = 0; e < 8; ++e) atomicAdd(&mycnt[binof((float)r[j][e])], 1u);
  if (two) {
#pragma unroll
    for (int e = 0; e < 8; ++e) atomicAdd(&mycnt[binof((float)r4[e])], 1u);
  }
  wave_lds_fence();                       // histogram visible before reads
  // both selections' boundary buckets
  radix_find<NBIN / 64>(mycnt, KSEL1, &sres[wv][0]);
  radix_find<NBIN / 64>(mycnt, KSEL2, &sres[wv][2]);
  wave_lds_fence();                       // sres visible to all lanes
  const int b1 = (int)sres[wv][0], b2 = (int)sres[wv][2];
  const unsigned k1 = sres[wv][1], k2 = sres[wv][3];
  const unsigned c1 = mycnt[b1], c2 = mycnt[b2];
  const bool g1ok = (c1 <= GCAP), g2ok = (c2 <= GCAP);
  const float lo1 = (b1 == 0) ? -3.4e38f : ((float)b1 * (1.f / 256.f) - 1.f);
  const float hi1 = (b1 == NBIN - 1) ? 3.4e38f : ((float)(b1 + 1) * (1.f / 256.f) - 1.f);
  const float lo2 = (b2 == 0) ? -3.4e38f : ((float)b2 * (1.f / 256.f) - 1.f);
  const float hi2 = (b2 == NBIN - 1) ? 3.4e38f : ((float)(b2 + 1) * (1.f / 256.f) - 1.f);
  // gather boundary-bucket elements from registers
#pragma unroll
  for (int j = 0; j < 4; ++j)
#pragma unroll
    for (int e = 0; e < 8; ++e) {
      float v = (float)r[j][e];
      if (g1ok && v >= lo1 && v < hi1) buf[wv][0][atomicAdd(&bcnt[wv][0], 1u)] = v;
      if (g2ok && v >= lo2 && v < hi2) buf[wv][1][atomicAdd(&bcnt[wv][1], 1u)] = v;
    }
  if (two) {
#pragma unroll
    for (int e = 0; e < 8; ++e) {
      float v = (float)r4[e];
      if (g1ok && v >= lo1 && v < hi1) buf[wv][0][atomicAdd(&bcnt[wv][0], 1u)] = v;
      if (g2ok && v >= lo2 && v < hi2) buf[wv][1][atomicAdd(&bcnt[wv][1], 1u)] = v;
    }
  }
  wave_lds_fence();                       // gathered buf visible
  // exact k-th within boundary bucket (both sels, serial per wave)
#pragma unroll
  for (int sel = 0; sel < 2; ++sel) {
    const unsigned kk = sel ? k2 : k1;
    const int bb = sel ? b2 : b1;
    const unsigned cc = sel ? c2 : c1;
    if (cc <= GCAP) {
      for (unsigned i = lane; i < cc; i += 64) {
        float xv = buf[wv][sel][i];
        unsigned g = 0, m = 0;
        for (unsigned j2 = 0; j2 < cc; ++j2) {
          float yv = buf[wv][sel][j2];   // same-address broadcast
          g += (yv > xv) ? 1u : 0u;
          m += (yv == xv) ? 1u : 0u;
        }
        if (g < kk && kk <= g + m) tthr[wv][sel] = xv;
      }
    } else {
      // exact fallback: re-read row from global (degenerate data only)
      for (int i = lane; i < NTOK; i += 64) {
        float xv = (float)sc[base + i];
        if (binof(xv) != bb) continue;
        unsigned g = 0, m = 0;
        for (int j2 = 0; j2 < NTOK; ++j2) {
          float yv = (float)sc[base + j2];
          if (binof(yv) != bb) continue;
          g += (yv > xv) ? 1u : 0u;
          m += (yv == xv) ? 1u : 0u;
        }
        if (g < kk && kk <= g + m) tthr[wv][sel] = xv;
      }
    }
  }
  wave_lds_fence();                       // tthr visible
  // D = suffix of cnt[b]*exp(center_b) + exact boundary partial (both sels)
  float D[2];
#pragma unroll
  for (int sel = 0; sel < 2; ++sel) {
    const int bb = sel ? b2 : b1;
    const unsigned cc = sel ? c2 : c1;
    const float t = tthr[wv][sel];
    float ps = 0.f;
    if (cc <= GCAP) {
      for (unsigned i = lane; i < cc; i += 64) {
        float xv = buf[wv][sel][i];
        if (xv >= t) ps += __expf(xv);
      }
    } else {
      for (int i = lane; i < NTOK; i += 64) {
        float xv = (float)sc[base + i];
        if (binof(xv) == bb && xv >= t) ps += __expf(xv);
      }
    }
    for (int b = bb + 1 + lane; b < NBIN; b += 64)
      ps += (float)mycnt[b] * __expf((float)b * (1.f / 256.f) + (0.5f / 256.f) - 1.f);
#pragma unroll
    for (int off = 32; off; off >>= 1) ps += __shfl_down(ps, off);
    D[sel] = ps;
  }
  if (lane == 0) {
    float* st = stats + (size_t)row * 8;
    st[0] = 0.f;
    st[1] = tthr[wv][0];
    st[2] = tthr[wv][1];
    st[3] = w1p[0] / D[0];
    st[4] = w2p[0] / D[1];
  }
}

// ---------------------------------------------------------------------------
// Kernel F: PV via MFMA, zero LDS. Wave w of each block owns a 16(n) x 32(d)
// output tile. m-split over blockIdx.y, atomicAdd combine into zeroed oat.
#define MSPLIT 4
__global__ __launch_bounds__(256) void pv_mfma_kernel(const _Float16* __restrict__ sc,
                                                      const _Float16* __restrict__ vtb,
                                                      const float* __restrict__ stats,
                                                      float* __restrict__ oat, int bh0) {
  const int w = threadIdx.x >> 6;
  const int l = threadIdx.x & 63;
  const int z = blockIdx.z;
  const int gbh = bh0 + z;
  const int b = gbh >> 3, h = gbh & 7;
  const int n0 = blockIdx.x * 64 + w * 16;
  const int row = l & 15;            // A row / C col (d within half)
  const int kg = l >> 4;             // k-group
  const int n = n0 + row;
  const float* st = stats + ((size_t)z * NTOK + n) * 8;
  const float mx = st[0], t1 = st[1], t2 = st[2], w1d = st[3], w2d = st[4];
  const _Float16* srow = sc + ((size_t)z * NTOK + n) * NTOK;
  const _Float16* v0 = vtb + ((size_t)gbh * HDIM + row) * NTOK;
  const _Float16* v1 = v0 + 16 * NTOK;
  f32x4 acc0 = {0.f, 0.f, 0.f, 0.f};
  f32x4 acc1 = {0.f, 0.f, 0.f, 0.f};
  const int msteps = (NTOK / 32) / MSPLIT;   // 18
  int m0 = blockIdx.y * msteps * 32 + kg * 8;
#pragma unroll 2
  for (int s = 0; s < msteps; ++s, m0 += 32) {
    f16x8 sv8 = *(const f16x8*)(srow + m0);
    f16x8 afr;
#pragma unroll
    for (int i = 0; i < 8; ++i) {
      float sv = (float)sv8[i];
      float e = __expf(sv - mx);
      float wgt = (sv >= t1 ? w1d : 0.f) + (sv >= t2 ? w2d : 0.f);
      afr[i] = (_Float16)(e * wgt);
    }
    f16x8 bfr0 = *(const f16x8*)(v0 + m0);
    f16x8 bfr1 = *(const f16x8*)(v1 + m0);
    acc0 = __builtin_amdgcn_mfma_f32_16x16x32_f16(afr, bfr0, acc0, 0, 0, 0);
    acc1 = __builtin_amdgcn_mfma_f32_16x16x32_f16(afr, bfr1, acc1, 0, 0, 0);
  }
  // C/D layout: col = lane&15 (=row var), row = (lane>>4)*4 + reg
#pragma unroll
  for (int r = 0; r < 4; ++r) {
    int nn = n0 + kg * 4 + r;
    float* dst = &oat[((size_t)(b * NTOK + nn)) * CC + h * HDIM];
    atomicAdd(&dst[row], acc0[r]);
    atomicAdd(&dst[16 + row], acc1[r]);
  }
}

// ---------------------------------------------------------------------------
extern "C" void kernel_launch(void* const* d_in, const int* in_sizes, int n_in,
                              void* d_out, int out_size, void* d_ws, size_t ws_size,
                              hipStream_t stream) {
  const float* x     = (const float*)d_in[0];
  const float* y     = (const float*)d_in[1];
  const float* Wq    = (const float*)d_in[2];
  const float* Wkv   = (const float*)d_in[3];
  const float* Wproj = (const float*)d_in[4];
  const float* bproj = (const float*)d_in[5];
  const float* gamma = (const float*)d_in[6];
  const float* beta  = (const float*)d_in[7];
  const float* aw1   = (const float*)d_in[8];
  const float* aw2   = (const float*)d_in[9];

  float* ws = (float*)d_ws;
  const size_t SZ_PLANE = (size_t)BB * CC * NTOK;          // 1,179,648
  const size_t SZ_TBL = (size_t)NBH * NTOK * HDIM;         // 1,179,648 (f16 elems)
  float* yp    = ws;                                       // [B,C,N]
  float* oat   = yp + SZ_PLANE;                            // [B,N,C]
  float* stats = oat + SZ_PLANE;                           // [16*2304, 8]
  _Float16* yth = (_Float16*)(stats + (size_t)NBH * NTOK * 8);
  _Float16* ytl = yth + SZ_PLANE;
  _Float16* xh  = ytl + SZ_PLANE;
  _Float16* xl  = xh + SZ_PLANE;
  _Float16* wqh = xl + SZ_PLANE;                           // [256][256]
  _Float16* wql = wqh + CC * CC;
  _Float16* wkvh = wql + CC * CC;                          // [512][256]
  _Float16* wkvl = wkvh + 2 * CC * CC;
  _Float16* wph = wkvl + 2 * CC * CC;                      // [256][256]
  _Float16* wpl = wph + CC * CC;
  _Float16* qh  = wpl + CC * CC;                           // [16][2304][32]
  _Float16* ql  = qh + SZ_TBL;
  _Float16* kh  = ql + SZ_TBL;
  _Float16* kl  = kh + SZ_TBL;
  _Float16* vtb = kl + SZ_TBL;                             // [16][32][2304]
  _Float16* sc  = vtb + SZ_TBL;                            // [CH, N, N] f16

  const long long fixed_f = (long long)((float*)sc - ws);
  const long long avail_f = (long long)(ws_size / 4) - fixed_f;
  int CH = 16;
  while (CH > 1 && (long long)CH * NTOK * NTOK / 2 > avail_f) CH >>= 1;

  pool_kernel<<<dim3(BB * CC), 256, 0, stream>>>(y, yp);
  ln_kernel<<<dim3(NTOK / 32, BB), 256, 0, stream>>>(yp, gamma, beta, yth, ytl);
  xcast_kernel<<<dim3(NTOK / 64, CC / 64, BB), 256, 0, stream>>>(x, xh, xl);
  wtcast3_kernel<<<dim3(4 * CC), 256, 0, stream>>>(Wq, Wkv, Wproj, wqh, wql,
                                                   wkvh, wkvl, wph, wpl);
  gemm_hilo_kernel<0><<<dim3(BB * NTOK / 64, CC / 64), 256, 0, stream>>>(
      xh, xl, nullptr, wqh, wql, nullptr, qh, ql, nullptr, nullptr);
  gemm_hilo_kernel<1><<<dim3(BB * NTOK / 64, 2 * CC / 64), 256, 0, stream>>>(
      yth, ytl, nullptr, wkvh, wkvl, nullptr, kh, kl, vtb, nullptr);

  hipMemsetAsync(oat, 0, SZ_PLANE * sizeof(float), stream);

  const int nch = NBH / CH;
  for (int ch = 0; ch < nch; ++ch) {
    int bh0 = ch * CH;
    score_mfma_kernel<<<dim3(NTOK / 64, NTOK / (SMSTEP * 64), CH), 256, 0, stream>>>(
        qh, ql, kh, kl, sc, bh0);
    select_kernel<<<dim3(CH * NTOK / 4), 256, 0, stream>>>(sc, stats, aw1, aw2);
    pv_mfma_kernel<<<dim3(NTOK / 64, MSPLIT, CH), 256, 0, stream>>>(sc, vtb, stats, oat, bh0);
  }

  gemm_hilo_kernel<2><<<dim3(BB * NTOK / 64, CC / 64), 256, 0, stream>>>(
      nullptr, nullptr, oat, wph, wpl, bproj, nullptr, nullptr, nullptr, (float*)d_out);
}